// Round 10
// baseline (1769.806 us; speedup 1.0000x reference)
//
#include <hip/hip_runtime.h>
#include <math.h>

namespace {
constexpr int N_   = 10000;
constexpr int E_   = 80000;
constexpr int ORI_ = 12;
constexpr int HC_  = 768;   // ORI*C
constexpr float EPS_ = 1e-6f;
constexpr int NPB_ = 8;     // nodes per aggregation block (10000 % 8 == 0 via grid 1250)

// workspace layout (float units) — total ~172 MB (proven ws >= 187 MB)
constexpr size_t OFF_ORI  = 0;                        // 64
constexpr size_t OFF_FK   = 64;                       // 27648
constexpr size_t OFF_H    = OFF_FK + 27648;           // 7,680,000 (fp32 h)
constexpr size_t OFF_XNB  = OFF_H + 7680000;          // 3,840,000 (bf16 xn)
constexpr size_t OFF_RACC = OFF_XNB + 3840000;        // 240,000
constexpr size_t OFF_RP   = OFF_RACC + 240000;        // 10001 ints
constexpr size_t OFF_CUR  = OFF_RP + 10001;           // 10001 ints
constexpr size_t OFF_E0S  = OFF_CUR + 10001;          // 80000 ints
constexpr size_t OFF_REL  = ((OFF_E0S + 80000 + 3) / 4) * 4;   // 80000 float4
constexpr size_t OFF_WP   = ((OFF_REL + 320000 + 3) / 4) * 4;  // 3*32768 u16
constexpr size_t OFF_CKP  = OFF_WP + 49152;           // 3*4096 u16
constexpr size_t OFF_KB   = OFF_CKP + 6144;           // bf16 kb
constexpr size_t KB_F     = (size_t)E_ * ORI_ * 64 / 2;        // 30,720,000 f
}

typedef short bf16x8 __attribute__((ext_vector_type(8)));
typedef float f32x4  __attribute__((ext_vector_type(4)));

__device__ __forceinline__ float gelu_f(float x) {
  float x2 = x * x;
  float u  = x * fmaf(x2, 0.10294324f, 2.30220826f);
  float t  = __builtin_amdgcn_exp2f(u);
  float r  = __builtin_amdgcn_rcpf(t + 1.0f);
  return fmaf(-x, r, x);
}

__device__ __forceinline__ void wave_sync() {
  asm volatile("s_waitcnt lgkmcnt(0)" ::: "memory");
  __builtin_amdgcn_wave_barrier();
}

__device__ __forceinline__ float wave_sum64(float v) {
#pragma unroll
  for (int off = 32; off > 0; off >>= 1) v += __shfl_xor(v, off, 64);
  return v;
}

__device__ __forceinline__ unsigned short f2bf(float x) {
  unsigned u = __float_as_uint(x);
  unsigned r = (u + 0x7fffu + ((u >> 16) & 1u)) >> 16;  // RNE
  return (unsigned short)r;
}

// ---------------------------------------------------------------------------
// Setup: grid=3 (one block per layer), all weights LDS-staged.
// ---------------------------------------------------------------------------
__global__ __launch_bounds__(256) void k_setup(
    const float* __restrict__ fb_w1, const float* __restrict__ fb_b1,
    const float* __restrict__ fb_w2, const float* __restrict__ fb_b2,
    const float* __restrict__ fib_kw,
    float* __restrict__ g_ori, float* __restrict__ g_fk) {
  __shared__ float s_ori[36];
  __shared__ float s_w1[192];
  __shared__ float s_b1[64], s_b2[64];
  __shared__ float s_w2[4096];
  __shared__ float s_fib[4096];
  __shared__ float s_h1[144*64];
  __shared__ float s_kb[144*64];
  int tid = threadIdx.x;
  int i = blockIdx.x;
  if (tid < 12) {
    const double PI = 3.14159265358979323846;
    double th = fmod(PI * (double)tid * (1.0 + sqrt(5.0)), 2.0 * PI);
    double ph = acos(1.0 - 2.0 * ((double)tid + 0.5) / 12.0);
    float sx = (float)(sin(ph) * cos(th));
    float sy = (float)(sin(ph) * sin(th));
    float sz = (float)cos(ph);
    s_ori[tid*3+0]=sx; s_ori[tid*3+1]=sy; s_ori[tid*3+2]=sz;
    if (i == 0) { g_ori[tid*3+0]=sx; g_ori[tid*3+1]=sy; g_ori[tid*3+2]=sz; }
  }
  for (int k = tid; k < 4096; k += 256) { s_w2[k] = fb_w2[k]; s_fib[k] = fib_kw[i*4096 + k]; }
  if (tid < 192) s_w1[tid] = fb_w1[tid];
  if (tid < 64) { s_b1[tid] = fb_b1[tid]; s_b2[tid] = fb_b2[tid]; }
  __syncthreads();
  int wid = tid >> 6, lane = tid & 63;
  for (int r = wid; r < 144; r += 4) {
    int p = r / 12, o = r % 12;
    float s = s_ori[p*3+0]*s_ori[o*3+0] + s_ori[p*3+1]*s_ori[o*3+1] + s_ori[p*3+2]*s_ori[o*3+2];
    float f1 = s, f2 = s*s, f3 = s*s*s;
    float a1 = s_b1[lane] + f1*s_w1[lane] + f2*s_w1[64+lane] + f3*s_w1[128+lane];
    s_h1[r*64+lane] = gelu_f(a1);
  }
  __syncthreads();
  for (int r = wid; r < 144; r += 4) {
    float a2 = s_b2[lane];
    for (int j = 0; j < 64; ++j) a2 += s_h1[r*64+j] * s_w2[j*64+lane];
    s_kb[r*64+lane] = gelu_f(a2);
  }
  __syncthreads();
  for (int r = wid; r < 144; r += 4) {
    float acc = 0.f;
    for (int j = 0; j < 64; ++j) acc += s_kb[r*64+j] * s_fib[j*64+lane];
    g_fk[i*9216 + r*64 + lane] = acc;
  }
}

// ---------------------------------------------------------------------------
// Embed
// ---------------------------------------------------------------------------
__global__ __launch_bounds__(256) void k_embed(
    const float* __restrict__ x, const float* __restrict__ emb_w,
    float* __restrict__ h) {
  __shared__ float s_w[16*64];
  int tid = threadIdx.x;
  for (int i = tid; i < 16*64; i += 256) s_w[i] = emb_w[i];
  __syncthreads();
  int wid = tid >> 6, lane = tid & 63;
  int nw = gridDim.x * 4;
  for (int n = blockIdx.x*4 + wid; n < N_; n += nw) {
    float acc = 0.f;
#pragma unroll
    for (int k = 0; k < 16; ++k) acc += x[n*16+k] * s_w[k*64+lane];
#pragma unroll
    for (int o = 0; o < ORI_; ++o) h[n*HC_ + o*64 + lane] = acc;
  }
}

// ---------------------------------------------------------------------------
// CSR build
// ---------------------------------------------------------------------------
__global__ __launch_bounds__(256) void k_count(const int* __restrict__ ei, int* __restrict__ cnt) {
  int e = blockIdx.x*256 + threadIdx.x;
  if (e < E_) atomicAdd(&cnt[ei[E_ + e]], 1);
}

__global__ __launch_bounds__(256) void k_scan(int* __restrict__ cnt, int* __restrict__ row_ptr) {
  __shared__ int s_sum[256];
  int tid = threadIdx.x;
  int start = tid * 40, end = min(start + 40, N_);
  int s = 0;
  for (int i = start; i < end; ++i) s += cnt[i];
  s_sum[tid] = s;
  __syncthreads();
  if (tid == 0) {
    int run = 0;
    for (int i = 0; i < 256; ++i) { int t = s_sum[i]; s_sum[i] = run; run += t; }
  }
  __syncthreads();
  int run = s_sum[tid];
  for (int i = start; i < end; ++i) { int c = cnt[i]; row_ptr[i] = run; cnt[i] = run; run += c; }
  if (tid == 0) row_ptr[N_] = E_;
}

__global__ __launch_bounds__(256) void k_scatter(
    const float* __restrict__ pos, const int* __restrict__ ei,
    int* __restrict__ cursor, int* __restrict__ e0s, float4* __restrict__ rel4) {
  int e = blockIdx.x*256 + threadIdx.x;
  if (e >= E_) return;
  int a = ei[e], b = ei[E_ + e];
  int slot = atomicAdd(&cursor[b], 1);
  float rx = pos[a*3+0]-pos[b*3+0];
  float ry = pos[a*3+1]-pos[b*3+1];
  float rz = pos[a*3+2]-pos[b*3+2];
  e0s[slot] = a;
  rel4[slot] = make_float4(rx, ry, rz, __int_as_float(e));
}

__global__ __launch_bounds__(256) void k_sortbins(
    const int* __restrict__ row_ptr, int* __restrict__ e0s, float4* __restrict__ rel4) {
  int n = blockIdx.x*256 + threadIdx.x;
  if (n >= N_) return;
  int lo = row_ptr[n], hi = row_ptr[n+1];
  for (int i = lo + 1; i < hi; ++i) {
    float4 key = rel4[i]; int kk = __float_as_int(key.w); int ke = e0s[i];
    int j = i - 1;
    while (j >= lo && __float_as_int(rel4[j].w) > kk) {
      rel4[j+1] = rel4[j]; e0s[j+1] = e0s[j]; --j;
    }
    rel4[j+1] = key; e0s[j+1] = ke;
  }
}

// ---------------------------------------------------------------------------
// Basis: 1 row/thread -> bf16 kb, staged via swizzled LDS, coalesced writeout.
// ---------------------------------------------------------------------------
__global__ __launch_bounds__(256) void k_basis_bf(
    const float4* __restrict__ rel4,
    const float* __restrict__ sb_w1, const float* __restrict__ sb_b1,
    const float* __restrict__ sb_w2, const float* __restrict__ sb_b2,
    const float* __restrict__ g_ori, unsigned* __restrict__ kb_u) {
  __shared__ float s_w1[14*64];
  __shared__ float s_w2[64*64];
  __shared__ float s_b1[64];
  __shared__ float s_b2[64];
  __shared__ float s_ori[36];
  __shared__ unsigned s_out[256*32];   // 32 KB, swizzled
  int tid = threadIdx.x;
  for (int i = tid; i < 14*64; i += 256) s_w1[i] = sb_w1[i];
  for (int i = tid; i < 64*64; i += 256) s_w2[i] = sb_w2[i];
  if (tid < 64) { s_b1[tid] = sb_b1[tid]; s_b2[tid] = sb_b2[tid]; }
  if (tid < 36) s_ori[tid] = g_ori[tid];
  __syncthreads();
  int r = blockIdx.x*256 + tid;
  int s = r / 12, o = r - s*12;
  float4 rv = rel4[s];
  float rx = rv.x, ry = rv.y, rz = rv.z;
  float ox = s_ori[o*3+0], oy = s_ori[o*3+1], oz = s_ori[o*3+2];
  float i1 = rx*ox + ry*oy + rz*oz;
  float px = rx - i1*ox, py = ry - i1*oy, pz = rz - i1*oz;
  float i2 = sqrtf(px*px + py*py + pz*pz);
  float f[14];
  f[0]=i1; f[1]=i2; f[2]=i1*i1; f[3]=i1*i2; f[4]=i2*i1; f[5]=i2*i2;
  f[6]=f[2]*i1; f[7]=f[2]*i2; f[8]=f[3]*i1; f[9]=f[3]*i2;
  f[10]=f[4]*i1; f[11]=f[4]*i2; f[12]=f[5]*i1; f[13]=f[5]*i2;
  float h1[64];
#pragma unroll
  for (int j4 = 0; j4 < 16; ++j4) {
    float4 a = *(const float4*)&s_b1[j4*4];
#pragma unroll
    for (int p = 0; p < 14; ++p) {
      float4 w = *(const float4*)&s_w1[p*64 + j4*4];
      a.x += f[p]*w.x; a.y += f[p]*w.y; a.z += f[p]*w.z; a.w += f[p]*w.w;
    }
    h1[j4*4+0]=gelu_f(a.x); h1[j4*4+1]=gelu_f(a.y);
    h1[j4*4+2]=gelu_f(a.z); h1[j4*4+3]=gelu_f(a.w);
  }
  unsigned outw[32];
#pragma unroll 1
  for (int c4 = 0; c4 < 16; ++c4) {
    float4 a = *(const float4*)&s_b2[c4*4];
#pragma unroll
    for (int j = 0; j < 64; ++j) {
      float4 w = *(const float4*)&s_w2[j*64 + c4*4];
      float hv = h1[j];
      a.x += hv*w.x; a.y += hv*w.y; a.z += hv*w.z; a.w += hv*w.w;
    }
    a.x = gelu_f(a.x); a.y = gelu_f(a.y); a.z = gelu_f(a.z); a.w = gelu_f(a.w);
    outw[c4*2+0] = (unsigned)f2bf(a.x) | ((unsigned)f2bf(a.y) << 16);
    outw[c4*2+1] = (unsigned)f2bf(a.z) | ((unsigned)f2bf(a.w) << 16);
  }
  uint4* s_out4 = (uint4*)s_out;
#pragma unroll
  for (int g = 0; g < 8; ++g) {
    s_out4[tid*8 + (g ^ (tid & 7))] =
        make_uint4(outw[g*4+0], outw[g*4+1], outw[g*4+2], outw[g*4+3]);
  }
  __syncthreads();
  size_t base = (size_t)blockIdx.x * 8192;
  for (int k = tid; k < 8192; k += 256) {
    int row = k >> 5, c = k & 31, g = c >> 2, q = c & 3;
    kb_u[base + k] = s_out[(row << 5) + ((g ^ (row & 7)) << 2) + q];
  }
}

// ---------------------------------------------------------------------------
// Pack weights into bf16 MFMA fragment order (once): MLP w1/w2 + conv_kw.
// ---------------------------------------------------------------------------
__global__ __launch_bounds__(256) void k_pack(
    const float* __restrict__ l1_w, const float* __restrict__ l2_w,
    const float* __restrict__ conv_kw,
    unsigned short* __restrict__ wp, unsigned short* __restrict__ ckp) {
  int i = blockIdx.x;
  unsigned short* w1p = wp + (size_t)i*32768;
  unsigned short* w2p = w1p + 16384;
  const float* w1 = l1_w + i*16384;
  const float* w2 = l2_w + i*16384;
  for (int k = threadIdx.x; k < 16384; k += 256) {
    int c = k >> 8, j = k & 255;          // w1[c][j]
    int jt = j >> 4, hh = c >> 5, gg = (c >> 3) & 3, kp = c & 7;
    int l = gg*16 + (j & 15);
    w1p[jt*1024 + hh*512 + l*8 + kp] = f2bf(w1[k]);
    int j2 = k >> 6, c2 = k & 63;         // w2[j2][c2]
    int ct = c2 >> 4, ks = j2 >> 5, g2 = (j2 >> 3) & 3, kp2 = j2 & 7;
    int l2 = g2*16 + (c2 & 15);
    w2p[(ct*8+ks)*512 + l2*8 + kp2] = f2bf(w2[k]);
  }
  const float* ck = conv_kw + i*4096;
  unsigned short* ckpi = ckp + (size_t)i*4096;
  for (int idx = threadIdx.x; idx < 4096; idx += 256) {
    int fi = idx >> 9, l = (idx >> 3) & 63, kp = idx & 7;
    int ct = fi >> 1, ks = fi & 1, g = l >> 4, m = l & 15;
    ckpi[idx] = f2bf(ck[(ks*32 + g*8 + kp)*64 + ct*16 + m]);
  }
}

// ---------------------------------------------------------------------------
// FUSED aggregation v2: block = 8 consecutive nodes (their kb rows are one
// contiguous range).  Row-tiles round-robin across 4 waves (~12 tiles/wave):
// kb A-frags from global, ck B-frags in VGPRs, 8 MFMAs -> kc tile; per row
// multiply by gathered h[e0,o,c], ds-atomic into s_x1[node][o][c]; then
// conv-mix + LN for the 8 nodes.
// ---------------------------------------------------------------------------
__global__ __launch_bounds__(256) void k_aggr_v2(
    const unsigned short* __restrict__ kb, const int* __restrict__ row_ptr,
    const int* __restrict__ e0s, const unsigned short* __restrict__ ckp,
    const float* __restrict__ g_fk_i, const float* __restrict__ conv_b,
    const float* __restrict__ ln_s, const float* __restrict__ ln_b,
    const float* __restrict__ h, unsigned short* __restrict__ xnb) {
  __shared__ float s_fk[9216];
  __shared__ float s_x1[NPB_*768];
  __shared__ float s_cb[64], s_ls[64], s_lb[64];
  __shared__ int s_rp[NPB_+1];
  int tid = threadIdx.x;
  int wid = tid >> 6, lane = tid & 63;
  int g = lane >> 4, m = lane & 15;
  for (int i = tid; i < 9216; i += 256) s_fk[i] = g_fk_i[i];
  for (int i = tid; i < NPB_*768; i += 256) s_x1[i] = 0.f;
  if (tid < 64) { s_cb[tid]=conv_b[tid]; s_ls[tid]=ln_s[tid]; s_lb[tid]=ln_b[tid]; }
  if (tid <= NPB_) s_rp[tid] = row_ptr[blockIdx.x*NPB_ + tid];
  bf16x8 ckf[8];
#pragma unroll
  for (int fi = 0; fi < 8; ++fi) ckf[fi] = *(const bf16x8*)(ckp + fi*512 + lane*8);
  __syncthreads();
  int slo = s_rp[0], shi = s_rp[NPB_];
  int R = (shi - slo) * 12;
  size_t base = (size_t)slo * 12;
#pragma unroll 1
  for (int rt = wid; rt*16 < R; rt += 4) {
    int rbase = rt * 16;
    const unsigned short* arow = kb + (base + rbase + m)*64 + g*8;
    bf16x8 a0 = *(const bf16x8*)(arow);
    bf16x8 a1 = *(const bf16x8*)(arow + 32);
    f32x4 acc[4];
#pragma unroll
    for (int ct = 0; ct < 4; ++ct) {
      acc[ct] = (f32x4){0.f, 0.f, 0.f, 0.f};
      acc[ct] = __builtin_amdgcn_mfma_f32_16x16x32_bf16(a0, ckf[ct*2+0], acc[ct], 0, 0, 0);
      acc[ct] = __builtin_amdgcn_mfma_f32_16x16x32_bf16(a1, ckf[ct*2+1], acc[ct], 0, 0, 0);
    }
#pragma unroll
    for (int reg = 0; reg < 4; ++reg) {
      int rloc = rbase + 4*g + reg;
      if (rloc < R) {
        int sl = rloc / 12;
        int o  = rloc - sl*12;
        int sg = slo + sl;
        int e0 = e0s[sg];
        int ln = 0;
#pragma unroll
        for (int q = 1; q < NPB_; ++q) ln += (sg >= s_rp[q]) ? 1 : 0;
        const float* hrow = h + (size_t)e0*HC_ + o*64 + m;
        float* xo = &s_x1[ln*768 + o*64 + m];
#pragma unroll
        for (int ct = 0; ct < 4; ++ct) {
          atomicAdd(xo + ct*16, acc[ct][reg] * hrow[ct*16]);
        }
      }
    }
  }
  __syncthreads();
  for (int idx = wid; idx < NPB_*12; idx += 4) {
    int ln = idx & (NPB_-1);
    int p  = idx >> 3;
    float a = 0.f;
#pragma unroll
    for (int o = 0; o < 12; ++o) a += s_x1[ln*768 + o*64 + lane] * s_fk[(p*12+o)*64 + lane];
    a = a * (1.0f/12.0f) + s_cb[lane];
    float s1 = wave_sum64(a);
    float s2 = wave_sum64(a*a);
    float mu = s1 * (1.0f/64.0f);
    float var = s2 * (1.0f/64.0f) - mu*mu;
    float v = (a - mu) * rsqrtf(var + EPS_) * s_ls[lane] + s_lb[lane];
    xnb[(size_t)(blockIdx.x*NPB_ + ln)*HC_ + p*64 + lane] = f2bf(v);
  }
}

// ---------------------------------------------------------------------------
// Node MLP via MFMA (bf16)
// ---------------------------------------------------------------------------
__global__ __launch_bounds__(512) void k_mlp_mfma(
    const unsigned short* __restrict__ xnb, float* __restrict__ h,
    const unsigned short* __restrict__ w1p, const unsigned short* __restrict__ w2p,
    const float* __restrict__ l1_b, const float* __restrict__ l2_b,
    const float* __restrict__ ro_w, const float* __restrict__ ro_b,
    float* __restrict__ racc) {
  __shared__ unsigned short s_w1p[16384];
  __shared__ unsigned short s_w2p[16384];
  __shared__ float s_b1[256];
  __shared__ float s_b2[64];
  __shared__ float s_ro[128];
  __shared__ unsigned short s_hm[8][16*272];
  int tid = threadIdx.x;
  {
    const uint4* a4 = (const uint4*)w1p;  uint4* d4 = (uint4*)s_w1p;
    const uint4* b4 = (const uint4*)w2p;  uint4* e4 = (uint4*)s_w2p;
    for (int k = tid; k < 2048; k += 512) { d4[k] = a4[k]; e4[k] = b4[k]; }
  }
  if (tid < 256) s_b1[tid] = l1_b[tid];
  if (tid < 64)  s_b2[tid] = l2_b[tid];
  if (tid < 128) s_ro[tid] = ro_w[tid];
  __syncthreads();
  int wid = tid >> 6, lane = tid & 63;
  int g = lane >> 4, m = lane & 15;
  float rb0 = ro_b[0], rb1 = ro_b[1];
  float b2v[4], rw0[4], rw1[4];
#pragma unroll
  for (int ct = 0; ct < 4; ++ct) {
    b2v[ct] = s_b2[ct*16 + m];
    rw0[ct] = s_ro[(ct*16+m)*2+0];
    rw1[ct] = s_ro[(ct*16+m)*2+1];
  }
  unsigned short* hm = s_hm[wid];
  int nwg = gridDim.x * 8;
  for (int rg = blockIdx.x*8 + wid; rg < 7500; rg += nwg) {
    int r0 = rg * 16;
    bf16x8 xb0 = *(const bf16x8*)(xnb + (size_t)(r0 + m)*64 + g*8);
    bf16x8 xb1 = *(const bf16x8*)(xnb + (size_t)(r0 + m)*64 + 32 + g*8);
    wave_sync();
#pragma unroll 4
    for (int jt = 0; jt < 16; ++jt) {
      bf16x8 a0 = *(const bf16x8*)(s_w1p + jt*1024 + lane*8);
      bf16x8 a1 = *(const bf16x8*)(s_w1p + jt*1024 + 512 + lane*8);
      f32x4 acc = {0.f, 0.f, 0.f, 0.f};
      acc = __builtin_amdgcn_mfma_f32_16x16x32_bf16(a0, xb0, acc, 0, 0, 0);
      acc = __builtin_amdgcn_mfma_f32_16x16x32_bf16(a1, xb1, acc, 0, 0, 0);
      float4 b1v = *(const float4*)&s_b1[jt*16 + g*4];
      float g0 = gelu_f(acc[0] + b1v.x);
      float g1 = gelu_f(acc[1] + b1v.y);
      float g2 = gelu_f(acc[2] + b1v.z);
      float g3 = gelu_f(acc[3] + b1v.w);
      unsigned wa = (unsigned)f2bf(g0) | ((unsigned)f2bf(g1) << 16);
      unsigned wb = (unsigned)f2bf(g2) | ((unsigned)f2bf(g3) << 16);
      *(uint2*)(hm + m*272 + jt*16 + g*4) = make_uint2(wa, wb);
    }
    wave_sync();
    f32x4 acc2[4];
#pragma unroll
    for (int ct = 0; ct < 4; ++ct) acc2[ct] = (f32x4){0.f, 0.f, 0.f, 0.f};
#pragma unroll
    for (int ks = 0; ks < 8; ++ks) {
      bf16x8 a2 = *(const bf16x8*)(hm + m*272 + ks*32 + g*8);
#pragma unroll
      for (int ct = 0; ct < 4; ++ct) {
        bf16x8 bf = *(const bf16x8*)(s_w2p + (ct*8+ks)*512 + lane*8);
        acc2[ct] = __builtin_amdgcn_mfma_f32_16x16x32_bf16(a2, bf, acc2[ct], 0, 0, 0);
      }
    }
    wave_sync();
#pragma unroll
    for (int reg = 0; reg < 4; ++reg) {
      int r = r0 + 4*g + reg;
      float v0 = 0.f, v1 = 0.f;
#pragma unroll
      for (int ct = 0; ct < 4; ++ct) {
        size_t idx = (size_t)r*64 + ct*16 + m;
        float hnew = acc2[ct][reg] + b2v[ct] + h[idx];
        h[idx] = hnew;
        v0 += hnew * rw0[ct];
        v1 += hnew * rw1[ct];
      }
#pragma unroll
      for (int off = 8; off > 0; off >>= 1) {
        v0 += __shfl_xor(v0, off, 16);
        v1 += __shfl_xor(v1, off, 16);
      }
      if (m == 0) {
        racc[r*2+0] += v0 + rb0;
        racc[r*2+1] += v1 + rb1;
      }
    }
  }
}

// ---------------------------------------------------------------------------
// Final segment-sum
// ---------------------------------------------------------------------------
__global__ __launch_bounds__(256) void k_final(
    const float* __restrict__ racc, const int* __restrict__ batch,
    const float* __restrict__ g_ori, float* __restrict__ out) {
  __shared__ float s_part[32];
  __shared__ float s_ori[36];
  int tid = threadIdx.x;
  if (tid < 32) s_part[tid] = 0.f;
  if (tid < 36) s_ori[tid] = g_ori[tid];
  __syncthreads();
  const float sc = 1.0f / 36.0f;
  for (int n = blockIdx.x*256 + tid; n < N_; n += gridDim.x*256) {
    int bt = batch[n];
    float ss = 0.f, v0 = 0.f, v1 = 0.f, v2 = 0.f;
#pragma unroll
    for (int o = 0; o < 12; ++o) {
      float r0 = racc[n*24 + o*2 + 0];
      float r1 = racc[n*24 + o*2 + 1];
      ss += r0;
      v0 += r1 * s_ori[o*3+0];
      v1 += r1 * s_ori[o*3+1];
      v2 += r1 * s_ori[o*3+2];
    }
    atomicAdd(&s_part[bt], ss*sc);
    atomicAdd(&s_part[8 + bt*3 + 0], v0*sc);
    atomicAdd(&s_part[8 + bt*3 + 1], v1*sc);
    atomicAdd(&s_part[8 + bt*3 + 2], v2*sc);
  }
  __syncthreads();
  if (tid < 32) atomicAdd(&out[tid], s_part[tid]);
}

extern "C" void kernel_launch(void* const* d_in, const int* in_sizes, int n_in,
                              void* d_out, int out_size, void* d_ws, size_t ws_size,
                              hipStream_t stream) {
  const float* pos    = (const float*)d_in[0];
  const float* x      = (const float*)d_in[1];
  const int*   ei     = (const int*)d_in[2];
  const int*   batch  = (const int*)d_in[3];
  const float* sb_w1  = (const float*)d_in[4];
  const float* sb_b1  = (const float*)d_in[5];
  const float* sb_w2  = (const float*)d_in[6];
  const float* sb_b2  = (const float*)d_in[7];
  const float* fb_w1  = (const float*)d_in[8];
  const float* fb_b1  = (const float*)d_in[9];
  const float* fb_w2  = (const float*)d_in[10];
  const float* fb_b2  = (const float*)d_in[11];
  const float* emb_w  = (const float*)d_in[12];
  const float* conv_kw= (const float*)d_in[13];
  const float* fib_kw = (const float*)d_in[14];
  const float* conv_b = (const float*)d_in[15];
  const float* ln_s   = (const float*)d_in[16];
  const float* ln_b   = (const float*)d_in[17];
  const float* l1_w   = (const float*)d_in[18];
  const float* l1_b   = (const float*)d_in[19];
  const float* l2_w   = (const float*)d_in[20];
  const float* l2_b   = (const float*)d_in[21];
  const float* ro_w   = (const float*)d_in[22];
  const float* ro_b   = (const float*)d_in[23];

  float* ws_f   = (float*)d_ws;
  float* g_ori  = ws_f + OFF_ORI;
  float* g_fk   = ws_f + OFF_FK;
  float* g_h    = ws_f + OFF_H;
  unsigned short* g_xnb = (unsigned short*)(ws_f + OFF_XNB);
  float* g_racc = ws_f + OFF_RACC;
  int*   row_ptr= (int*)(ws_f + OFF_RP);
  int*   cursor = (int*)(ws_f + OFF_CUR);
  int*   e0s    = (int*)(ws_f + OFF_E0S);
  float4* rel4  = (float4*)(ws_f + OFF_REL);
  unsigned short* g_wp  = (unsigned short*)(ws_f + OFF_WP);
  unsigned short* g_ckp = (unsigned short*)(ws_f + OFF_CKP);
  unsigned short* g_kb  = (unsigned short*)(ws_f + OFF_KB);
  unsigned*       kb_u  = (unsigned*)g_kb;
  float* out_f  = (float*)d_out;

  (void)hipMemsetAsync(g_racc, 0, 240000*sizeof(float), stream);
  k_setup<<<3, 256, 0, stream>>>(fb_w1, fb_b1, fb_w2, fb_b2, fib_kw, g_ori, g_fk);
  k_embed<<<512, 256, 0, stream>>>(x, emb_w, g_h);

  (void)hipMemsetAsync(cursor, 0, (N_+1)*sizeof(int), stream);
  k_count<<<(E_+255)/256, 256, 0, stream>>>(ei, cursor);
  k_scan<<<1, 256, 0, stream>>>(cursor, row_ptr);
  k_scatter<<<(E_+255)/256, 256, 0, stream>>>(pos, ei, cursor, e0s, rel4);
  k_sortbins<<<(N_+255)/256, 256, 0, stream>>>(row_ptr, e0s, rel4);
  k_pack<<<3, 256, 0, stream>>>(l1_w, l2_w, conv_kw, g_wp, g_ckp);
  k_basis_bf<<<(E_*ORI_)/256, 256, 0, stream>>>(rel4, sb_w1, sb_b1, sb_w2, sb_b2, g_ori, kb_u);
  for (int i = 0; i < 3; ++i) {
    k_aggr_v2<<<N_/NPB_, 256, 0, stream>>>(g_kb, row_ptr, e0s, g_ckp + (size_t)i*4096,
                                           g_fk + i*9216, conv_b + i*64,
                                           ln_s + i*64, ln_b + i*64, g_h, g_xnb);
    k_mlp_mfma<<<256, 512, 0, stream>>>(g_xnb, g_h,
                                        g_wp + (size_t)i*32768, g_wp + (size_t)i*32768 + 16384,
                                        l1_b + i*256, l2_b + i*64,
                                        ro_w + i*128, ro_b + i*2, g_racc);
  }
  (void)hipMemsetAsync(out_f, 0, 32*sizeof(float), stream);
  k_final<<<128, 256, 0, stream>>>(g_racc, batch, g_ori, out_f);
}

// Round 11
// 1105.969 us; speedup vs baseline: 1.6002x; 1.6002x over previous
//
#include <hip/hip_runtime.h>
#include <math.h>

namespace {
constexpr int N_   = 10000;
constexpr int E_   = 80000;
constexpr int ORI_ = 12;
constexpr int HC_  = 768;   // ORI*C
constexpr float EPS_ = 1e-6f;

// workspace layout (float units) — total ~172 MB (proven ws >= 187 MB)
constexpr size_t OFF_ORI  = 0;                        // 64
constexpr size_t OFF_FK   = 64;                       // 27648
constexpr size_t OFF_H    = OFF_FK + 27648;           // 7,680,000 (fp32 h)
constexpr size_t OFF_XNB  = OFF_H + 7680000;          // 3,840,000 (bf16 xn)
constexpr size_t OFF_RACC = OFF_XNB + 3840000;        // 240,000
constexpr size_t OFF_RP   = OFF_RACC + 240000;        // 10001 ints
constexpr size_t OFF_CUR  = OFF_RP + 10001;           // 10001 ints
constexpr size_t OFF_E0S  = OFF_CUR + 10001;          // 80000 ints
constexpr size_t OFF_REL  = ((OFF_E0S + 80000 + 3) / 4) * 4;   // 80000 float4
constexpr size_t OFF_WP   = ((OFF_REL + 320000 + 3) / 4) * 4;  // 3*32768 u16 (MLP)
constexpr size_t OFF_CKP  = OFF_WP + 49152;           // 3*2048 u32 f16-pairs
constexpr size_t OFF_KB   = OFF_CKP + 6144;           // f16 kb: 960000 rows * 32 u32
constexpr size_t KB_F     = (size_t)E_ * ORI_ * 64 / 2;        // 30,720,000 f
}

typedef short bf16x8 __attribute__((ext_vector_type(8)));
typedef float f32x4  __attribute__((ext_vector_type(4)));
typedef _Float16 half2v __attribute__((ext_vector_type(2)));

#if __has_builtin(__builtin_amdgcn_fdot2)
#define FDOT2(a,b,c) __builtin_amdgcn_fdot2((a),(b),(c),false)
#else
__device__ __forceinline__ float FDOT2(half2v a, half2v b, float c) {
  return c + (float)a.x*(float)b.x + (float)a.y*(float)b.y;
}
#endif

__device__ __forceinline__ float gelu_f(float x) {
  float x2 = x * x;
  float u  = x * fmaf(x2, 0.10294324f, 2.30220826f);
  float t  = __builtin_amdgcn_exp2f(u);
  float r  = __builtin_amdgcn_rcpf(t + 1.0f);
  return fmaf(-x, r, x);
}

__device__ __forceinline__ void wave_sync() {
  asm volatile("s_waitcnt lgkmcnt(0)" ::: "memory");
  __builtin_amdgcn_wave_barrier();
}

__device__ __forceinline__ float wave_sum64(float v) {
#pragma unroll
  for (int off = 32; off > 0; off >>= 1) v += __shfl_xor(v, off, 64);
  return v;
}

__device__ __forceinline__ unsigned short f2bf(float x) {
  unsigned u = __float_as_uint(x);
  unsigned r = (u + 0x7fffu + ((u >> 16) & 1u)) >> 16;  // RNE
  return (unsigned short)r;
}

__device__ __forceinline__ unsigned short f2h(float x) {
  _Float16 h = (_Float16)x;
  unsigned short u;
  __builtin_memcpy(&u, &h, 2);
  return u;
}

__device__ __forceinline__ half2v u2h2(unsigned u) {
  half2v h;
  __builtin_memcpy(&h, &u, 4);
  return h;
}

// ---------------------------------------------------------------------------
// Setup: grid=3 (one block per layer), all weights LDS-staged.
// ---------------------------------------------------------------------------
__global__ __launch_bounds__(256) void k_setup(
    const float* __restrict__ fb_w1, const float* __restrict__ fb_b1,
    const float* __restrict__ fb_w2, const float* __restrict__ fb_b2,
    const float* __restrict__ fib_kw,
    float* __restrict__ g_ori, float* __restrict__ g_fk) {
  __shared__ float s_ori[36];
  __shared__ float s_w1[192];
  __shared__ float s_b1[64], s_b2[64];
  __shared__ float s_w2[4096];
  __shared__ float s_fib[4096];
  __shared__ float s_h1[144*64];
  __shared__ float s_kb[144*64];
  int tid = threadIdx.x;
  int i = blockIdx.x;
  if (tid < 12) {
    const double PI = 3.14159265358979323846;
    double th = fmod(PI * (double)tid * (1.0 + sqrt(5.0)), 2.0 * PI);
    double ph = acos(1.0 - 2.0 * ((double)tid + 0.5) / 12.0);
    float sx = (float)(sin(ph) * cos(th));
    float sy = (float)(sin(ph) * sin(th));
    float sz = (float)cos(ph);
    s_ori[tid*3+0]=sx; s_ori[tid*3+1]=sy; s_ori[tid*3+2]=sz;
    if (i == 0) { g_ori[tid*3+0]=sx; g_ori[tid*3+1]=sy; g_ori[tid*3+2]=sz; }
  }
  for (int k = tid; k < 4096; k += 256) { s_w2[k] = fb_w2[k]; s_fib[k] = fib_kw[i*4096 + k]; }
  if (tid < 192) s_w1[tid] = fb_w1[tid];
  if (tid < 64) { s_b1[tid] = fb_b1[tid]; s_b2[tid] = fb_b2[tid]; }
  __syncthreads();
  int wid = tid >> 6, lane = tid & 63;
  for (int r = wid; r < 144; r += 4) {
    int p = r / 12, o = r % 12;
    float s = s_ori[p*3+0]*s_ori[o*3+0] + s_ori[p*3+1]*s_ori[o*3+1] + s_ori[p*3+2]*s_ori[o*3+2];
    float f1 = s, f2 = s*s, f3 = s*s*s;
    float a1 = s_b1[lane] + f1*s_w1[lane] + f2*s_w1[64+lane] + f3*s_w1[128+lane];
    s_h1[r*64+lane] = gelu_f(a1);
  }
  __syncthreads();
  for (int r = wid; r < 144; r += 4) {
    float a2 = s_b2[lane];
    for (int j = 0; j < 64; ++j) a2 += s_h1[r*64+j] * s_w2[j*64+lane];
    s_kb[r*64+lane] = gelu_f(a2);
  }
  __syncthreads();
  for (int r = wid; r < 144; r += 4) {
    float acc = 0.f;
    for (int j = 0; j < 64; ++j) acc += s_kb[r*64+j] * s_fib[j*64+lane];
    g_fk[i*9216 + r*64 + lane] = acc;
  }
}

// ---------------------------------------------------------------------------
// Embed
// ---------------------------------------------------------------------------
__global__ __launch_bounds__(256) void k_embed(
    const float* __restrict__ x, const float* __restrict__ emb_w,
    float* __restrict__ h) {
  __shared__ float s_w[16*64];
  int tid = threadIdx.x;
  for (int i = tid; i < 16*64; i += 256) s_w[i] = emb_w[i];
  __syncthreads();
  int wid = tid >> 6, lane = tid & 63;
  int nw = gridDim.x * 4;
  for (int n = blockIdx.x*4 + wid; n < N_; n += nw) {
    float acc = 0.f;
#pragma unroll
    for (int k = 0; k < 16; ++k) acc += x[n*16+k] * s_w[k*64+lane];
#pragma unroll
    for (int o = 0; o < ORI_; ++o) h[n*HC_ + o*64 + lane] = acc;
  }
}

// ---------------------------------------------------------------------------
// CSR build
// ---------------------------------------------------------------------------
__global__ __launch_bounds__(256) void k_count(const int* __restrict__ ei, int* __restrict__ cnt) {
  int e = blockIdx.x*256 + threadIdx.x;
  if (e < E_) atomicAdd(&cnt[ei[E_ + e]], 1);
}

__global__ __launch_bounds__(256) void k_scan(int* __restrict__ cnt, int* __restrict__ row_ptr) {
  __shared__ int s_sum[256];
  int tid = threadIdx.x;
  int start = tid * 40, end = min(start + 40, N_);
  int s = 0;
  for (int i = start; i < end; ++i) s += cnt[i];
  s_sum[tid] = s;
  __syncthreads();
  if (tid == 0) {
    int run = 0;
    for (int i = 0; i < 256; ++i) { int t = s_sum[i]; s_sum[i] = run; run += t; }
  }
  __syncthreads();
  int run = s_sum[tid];
  for (int i = start; i < end; ++i) { int c = cnt[i]; row_ptr[i] = run; cnt[i] = run; run += c; }
  if (tid == 0) row_ptr[N_] = E_;
}

__global__ __launch_bounds__(256) void k_scatter(
    const float* __restrict__ pos, const int* __restrict__ ei,
    int* __restrict__ cursor, int* __restrict__ e0s, float4* __restrict__ rel4) {
  int e = blockIdx.x*256 + threadIdx.x;
  if (e >= E_) return;
  int a = ei[e], b = ei[E_ + e];
  int slot = atomicAdd(&cursor[b], 1);
  float rx = pos[a*3+0]-pos[b*3+0];
  float ry = pos[a*3+1]-pos[b*3+1];
  float rz = pos[a*3+2]-pos[b*3+2];
  e0s[slot] = a;
  rel4[slot] = make_float4(rx, ry, rz, __int_as_float(e));
}

__global__ __launch_bounds__(256) void k_sortbins(
    const int* __restrict__ row_ptr, int* __restrict__ e0s, float4* __restrict__ rel4) {
  int n = blockIdx.x*256 + threadIdx.x;
  if (n >= N_) return;
  int lo = row_ptr[n], hi = row_ptr[n+1];
  for (int i = lo + 1; i < hi; ++i) {
    float4 key = rel4[i]; int kk = __float_as_int(key.w); int ke = e0s[i];
    int j = i - 1;
    while (j >= lo && __float_as_int(rel4[j].w) > kk) {
      rel4[j+1] = rel4[j]; e0s[j+1] = e0s[j]; --j;
    }
    rel4[j+1] = key; e0s[j+1] = ke;
  }
}

// ---------------------------------------------------------------------------
// Basis: 1 row/thread -> F16 kb, staged via swizzled LDS, coalesced writeout.
// kb row = 32 u32 words; word k holds channels (2k, 2k+1) as f16 pair.
// ---------------------------------------------------------------------------
__global__ __launch_bounds__(256) void k_basis_f16(
    const float4* __restrict__ rel4,
    const float* __restrict__ sb_w1, const float* __restrict__ sb_b1,
    const float* __restrict__ sb_w2, const float* __restrict__ sb_b2,
    const float* __restrict__ g_ori, unsigned* __restrict__ kb_u) {
  __shared__ float s_w1[14*64];
  __shared__ float s_w2[64*64];
  __shared__ float s_b1[64];
  __shared__ float s_b2[64];
  __shared__ float s_ori[36];
  __shared__ unsigned s_out[256*32];   // 32 KB, swizzled
  int tid = threadIdx.x;
  for (int i = tid; i < 14*64; i += 256) s_w1[i] = sb_w1[i];
  for (int i = tid; i < 64*64; i += 256) s_w2[i] = sb_w2[i];
  if (tid < 64) { s_b1[tid] = sb_b1[tid]; s_b2[tid] = sb_b2[tid]; }
  if (tid < 36) s_ori[tid] = g_ori[tid];
  __syncthreads();
  int r = blockIdx.x*256 + tid;
  int s = r / 12, o = r - s*12;
  float4 rv = rel4[s];
  float rx = rv.x, ry = rv.y, rz = rv.z;
  float ox = s_ori[o*3+0], oy = s_ori[o*3+1], oz = s_ori[o*3+2];
  float i1 = rx*ox + ry*oy + rz*oz;
  float px = rx - i1*ox, py = ry - i1*oy, pz = rz - i1*oz;
  float i2 = sqrtf(px*px + py*py + pz*pz);
  float f[14];
  f[0]=i1; f[1]=i2; f[2]=i1*i1; f[3]=i1*i2; f[4]=i2*i1; f[5]=i2*i2;
  f[6]=f[2]*i1; f[7]=f[2]*i2; f[8]=f[3]*i1; f[9]=f[3]*i2;
  f[10]=f[4]*i1; f[11]=f[4]*i2; f[12]=f[5]*i1; f[13]=f[5]*i2;
  float h1[64];
#pragma unroll
  for (int j4 = 0; j4 < 16; ++j4) {
    float4 a = *(const float4*)&s_b1[j4*4];
#pragma unroll
    for (int p = 0; p < 14; ++p) {
      float4 w = *(const float4*)&s_w1[p*64 + j4*4];
      a.x += f[p]*w.x; a.y += f[p]*w.y; a.z += f[p]*w.z; a.w += f[p]*w.w;
    }
    h1[j4*4+0]=gelu_f(a.x); h1[j4*4+1]=gelu_f(a.y);
    h1[j4*4+2]=gelu_f(a.z); h1[j4*4+3]=gelu_f(a.w);
  }
  unsigned outw[32];
#pragma unroll 1
  for (int c4 = 0; c4 < 16; ++c4) {
    float4 a = *(const float4*)&s_b2[c4*4];
#pragma unroll
    for (int j = 0; j < 64; ++j) {
      float4 w = *(const float4*)&s_w2[j*64 + c4*4];
      float hv = h1[j];
      a.x += hv*w.x; a.y += hv*w.y; a.z += hv*w.z; a.w += hv*w.w;
    }
    a.x = gelu_f(a.x); a.y = gelu_f(a.y); a.z = gelu_f(a.z); a.w = gelu_f(a.w);
    outw[c4*2+0] = (unsigned)f2h(a.x) | ((unsigned)f2h(a.y) << 16);
    outw[c4*2+1] = (unsigned)f2h(a.z) | ((unsigned)f2h(a.w) << 16);
  }
  uint4* s_out4 = (uint4*)s_out;
#pragma unroll
  for (int g = 0; g < 8; ++g) {
    s_out4[tid*8 + (g ^ (tid & 7))] =
        make_uint4(outw[g*4+0], outw[g*4+1], outw[g*4+2], outw[g*4+3]);
  }
  __syncthreads();
  size_t base = (size_t)blockIdx.x * 8192;
  for (int k = tid; k < 8192; k += 256) {
    int row = k >> 5, c = k & 31, g = c >> 2, q = c & 3;
    kb_u[base + k] = s_out[(row << 5) + ((g ^ (row & 7)) << 2) + q];
  }
}

// ---------------------------------------------------------------------------
// Pack weights (once): MLP w1/w2 bf16 MFMA fragments + conv_kw f16-pairs.
// ckp2 layout: [pair p][c]: (ck[2p][c], ck[2p+1][c]) as f16x2 in one u32.
// ---------------------------------------------------------------------------
__global__ __launch_bounds__(256) void k_pack(
    const float* __restrict__ l1_w, const float* __restrict__ l2_w,
    const float* __restrict__ conv_kw,
    unsigned short* __restrict__ wp, unsigned* __restrict__ ckp2) {
  int i = blockIdx.x;
  unsigned short* w1p = wp + (size_t)i*32768;
  unsigned short* w2p = w1p + 16384;
  const float* w1 = l1_w + i*16384;
  const float* w2 = l2_w + i*16384;
  for (int k = threadIdx.x; k < 16384; k += 256) {
    int c = k >> 8, j = k & 255;          // w1[c][j]
    int jt = j >> 4, hh = c >> 5, gg = (c >> 3) & 3, kp = c & 7;
    int l = gg*16 + (j & 15);
    w1p[jt*1024 + hh*512 + l*8 + kp] = f2bf(w1[k]);
    int j2 = k >> 6, c2 = k & 63;         // w2[j2][c2]
    int ct = c2 >> 4, ks = j2 >> 5, g2 = (j2 >> 3) & 3, kp2 = j2 & 7;
    int l2 = g2*16 + (c2 & 15);
    w2p[(ct*8+ks)*512 + l2*8 + kp2] = f2bf(w2[k]);
  }
  const float* ck = conv_kw + i*4096;
  unsigned* cko = ckp2 + (size_t)i*2048;
  for (int idx = threadIdx.x; idx < 2048; idx += 256) {
    int p = idx >> 6, c = idx & 63;
    cko[idx] = (unsigned)f2h(ck[(2*p)*64 + c]) | ((unsigned)f2h(ck[(2*p+1)*64 + c]) << 16);
  }
}

// ---------------------------------------------------------------------------
// Aggregation (round-6 structure + fdot2): block = node, wave handles
// o = wid, wid+4, wid+8.  kb row staged to LDS by lanes<32 (coalesced),
// broadcast uint4 reads; per-lane kc via 32 v_dot2_f32_f16; acc += h * kc.
// Then conv-mix + LayerNorm -> bf16 xn.
// ---------------------------------------------------------------------------
__global__ __launch_bounds__(256) void k_aggr_f16(
    const unsigned* __restrict__ kb_u, const int* __restrict__ row_ptr,
    const int* __restrict__ e0s, const unsigned* __restrict__ ckp2,
    const float* __restrict__ g_fk_i, const float* __restrict__ conv_b,
    const float* __restrict__ ln_s, const float* __restrict__ ln_b,
    const float* __restrict__ h, unsigned short* __restrict__ xnb) {
  __shared__ float s_fk[9216];
  __shared__ float s_x1[768];
  __shared__ float s_cb[64], s_ls[64], s_lb[64];
  __shared__ unsigned s_row[4][2][32];
  int tid = threadIdx.x;
  int wid = tid >> 6, lane = tid & 63;
  for (int i = tid; i < 9216; i += 256) s_fk[i] = g_fk_i[i];
  if (tid < 64) { s_cb[tid]=conv_b[tid]; s_ls[tid]=ln_s[tid]; s_lb[tid]=ln_b[tid]; }
  half2v ckreg[32];
#pragma unroll
  for (int p = 0; p < 32; ++p) ckreg[p] = u2h2(ckp2[p*64 + lane]);
  __syncthreads();
  int n = blockIdx.x;
  int lo = row_ptr[n], hi = row_ptr[n+1];
  for (int o = wid; o < 12; o += 4) {
    float acc = 0.f;
    if (lo < hi) {
      unsigned kn = 0; float hn;
      if (lane < 32) kn = kb_u[(size_t)(lo*12 + o)*32 + lane];
      hn = h[(size_t)e0s[lo]*HC_ + o*64 + lane];
      int buf = 0;
      for (int s = lo; s < hi; ++s) {
        unsigned kcur = kn; float hcur = hn;
        if (s + 1 < hi) {
          if (lane < 32) kn = kb_u[(size_t)((s+1)*12 + o)*32 + lane];
          hn = h[(size_t)e0s[s+1]*HC_ + o*64 + lane];
        }
        if (lane < 32) s_row[wid][buf][lane] = kcur;
        wave_sync();
        float kc = 0.f;
        const uint4* rp = (const uint4*)s_row[wid][buf];
#pragma unroll
        for (int g = 0; g < 8; ++g) {
          uint4 v = rp[g];
          kc = FDOT2(u2h2(v.x), ckreg[g*4+0], kc);
          kc = FDOT2(u2h2(v.y), ckreg[g*4+1], kc);
          kc = FDOT2(u2h2(v.z), ckreg[g*4+2], kc);
          kc = FDOT2(u2h2(v.w), ckreg[g*4+3], kc);
        }
        acc += hcur * kc;
        buf ^= 1;
      }
    }
    s_x1[o*64 + lane] = acc;
  }
  __syncthreads();
  for (int p = wid; p < 12; p += 4) {
    float a = 0.f;
#pragma unroll
    for (int o = 0; o < 12; ++o) a += s_x1[o*64+lane] * s_fk[(p*12+o)*64 + lane];
    a = a * (1.0f/12.0f) + s_cb[lane];
    float s1 = wave_sum64(a);
    float s2 = wave_sum64(a*a);
    float mu = s1 * (1.0f/64.0f);
    float var = s2 * (1.0f/64.0f) - mu*mu;
    float v = (a - mu) * rsqrtf(var + EPS_) * s_ls[lane] + s_lb[lane];
    xnb[(size_t)n*HC_ + p*64 + lane] = f2bf(v);
  }
}

// ---------------------------------------------------------------------------
// Node MLP via MFMA (bf16)
// ---------------------------------------------------------------------------
__global__ __launch_bounds__(512) void k_mlp_mfma(
    const unsigned short* __restrict__ xnb, float* __restrict__ h,
    const unsigned short* __restrict__ w1p, const unsigned short* __restrict__ w2p,
    const float* __restrict__ l1_b, const float* __restrict__ l2_b,
    const float* __restrict__ ro_w, const float* __restrict__ ro_b,
    float* __restrict__ racc) {
  __shared__ unsigned short s_w1p[16384];
  __shared__ unsigned short s_w2p[16384];
  __shared__ float s_b1[256];
  __shared__ float s_b2[64];
  __shared__ float s_ro[128];
  __shared__ unsigned short s_hm[8][16*272];
  int tid = threadIdx.x;
  {
    const uint4* a4 = (const uint4*)w1p;  uint4* d4 = (uint4*)s_w1p;
    const uint4* b4 = (const uint4*)w2p;  uint4* e4 = (uint4*)s_w2p;
    for (int k = tid; k < 2048; k += 512) { d4[k] = a4[k]; e4[k] = b4[k]; }
  }
  if (tid < 256) s_b1[tid] = l1_b[tid];
  if (tid < 64)  s_b2[tid] = l2_b[tid];
  if (tid < 128) s_ro[tid] = ro_w[tid];
  __syncthreads();
  int wid = tid >> 6, lane = tid & 63;
  int g = lane >> 4, m = lane & 15;
  float rb0 = ro_b[0], rb1 = ro_b[1];
  float b2v[4], rw0[4], rw1[4];
#pragma unroll
  for (int ct = 0; ct < 4; ++ct) {
    b2v[ct] = s_b2[ct*16 + m];
    rw0[ct] = s_ro[(ct*16+m)*2+0];
    rw1[ct] = s_ro[(ct*16+m)*2+1];
  }
  unsigned short* hm = s_hm[wid];
  int nwg = gridDim.x * 8;
  for (int rg = blockIdx.x*8 + wid; rg < 7500; rg += nwg) {
    int r0 = rg * 16;
    bf16x8 xb0 = *(const bf16x8*)(xnb + (size_t)(r0 + m)*64 + g*8);
    bf16x8 xb1 = *(const bf16x8*)(xnb + (size_t)(r0 + m)*64 + 32 + g*8);
    wave_sync();
#pragma unroll 4
    for (int jt = 0; jt < 16; ++jt) {
      bf16x8 a0 = *(const bf16x8*)(s_w1p + jt*1024 + lane*8);
      bf16x8 a1 = *(const bf16x8*)(s_w1p + jt*1024 + 512 + lane*8);
      f32x4 acc = {0.f, 0.f, 0.f, 0.f};
      acc = __builtin_amdgcn_mfma_f32_16x16x32_bf16(a0, xb0, acc, 0, 0, 0);
      acc = __builtin_amdgcn_mfma_f32_16x16x32_bf16(a1, xb1, acc, 0, 0, 0);
      float4 b1v = *(const float4*)&s_b1[jt*16 + g*4];
      float g0 = gelu_f(acc[0] + b1v.x);
      float g1 = gelu_f(acc[1] + b1v.y);
      float g2 = gelu_f(acc[2] + b1v.z);
      float g3 = gelu_f(acc[3] + b1v.w);
      unsigned wa = (unsigned)f2bf(g0) | ((unsigned)f2bf(g1) << 16);
      unsigned wb = (unsigned)f2bf(g2) | ((unsigned)f2bf(g3) << 16);
      *(uint2*)(hm + m*272 + jt*16 + g*4) = make_uint2(wa, wb);
    }
    wave_sync();
    f32x4 acc2[4];
#pragma unroll
    for (int ct = 0; ct < 4; ++ct) acc2[ct] = (f32x4){0.f, 0.f, 0.f, 0.f};
#pragma unroll
    for (int ks = 0; ks < 8; ++ks) {
      bf16x8 a2 = *(const bf16x8*)(hm + m*272 + ks*32 + g*8);
#pragma unroll
      for (int ct = 0; ct < 4; ++ct) {
        bf16x8 bf = *(const bf16x8*)(s_w2p + (ct*8+ks)*512 + lane*8);
        acc2[ct] = __builtin_amdgcn_mfma_f32_16x16x32_bf16(a2, bf, acc2[ct], 0, 0, 0);
      }
    }
    wave_sync();
#pragma unroll
    for (int reg = 0; reg < 4; ++reg) {
      int r = r0 + 4*g + reg;
      float v0 = 0.f, v1 = 0.f;
#pragma unroll
      for (int ct = 0; ct < 4; ++ct) {
        size_t idx = (size_t)r*64 + ct*16 + m;
        float hnew = acc2[ct][reg] + b2v[ct] + h[idx];
        h[idx] = hnew;
        v0 += hnew * rw0[ct];
        v1 += hnew * rw1[ct];
      }
#pragma unroll
      for (int off = 8; off > 0; off >>= 1) {
        v0 += __shfl_xor(v0, off, 16);
        v1 += __shfl_xor(v1, off, 16);
      }
      if (m == 0) {
        racc[r*2+0] += v0 + rb0;
        racc[r*2+1] += v1 + rb1;
      }
    }
  }
}

// ---------------------------------------------------------------------------
// Final segment-sum
// ---------------------------------------------------------------------------
__global__ __launch_bounds__(256) void k_final(
    const float* __restrict__ racc, const int* __restrict__ batch,
    const float* __restrict__ g_ori, float* __restrict__ out) {
  __shared__ float s_part[32];
  __shared__ float s_ori[36];
  int tid = threadIdx.x;
  if (tid < 32) s_part[tid] = 0.f;
  if (tid < 36) s_ori[tid] = g_ori[tid];
  __syncthreads();
  const float sc = 1.0f / 36.0f;
  for (int n = blockIdx.x*256 + tid; n < N_; n += gridDim.x*256) {
    int bt = batch[n];
    float ss = 0.f, v0 = 0.f, v1 = 0.f, v2 = 0.f;
#pragma unroll
    for (int o = 0; o < 12; ++o) {
      float r0 = racc[n*24 + o*2 + 0];
      float r1 = racc[n*24 + o*2 + 1];
      ss += r0;
      v0 += r1 * s_ori[o*3+0];
      v1 += r1 * s_ori[o*3+1];
      v2 += r1 * s_ori[o*3+2];
    }
    atomicAdd(&s_part[bt], ss*sc);
    atomicAdd(&s_part[8 + bt*3 + 0], v0*sc);
    atomicAdd(&s_part[8 + bt*3 + 1], v1*sc);
    atomicAdd(&s_part[8 + bt*3 + 2], v2*sc);
  }
  __syncthreads();
  if (tid < 32) atomicAdd(&out[tid], s_part[tid]);
}

extern "C" void kernel_launch(void* const* d_in, const int* in_sizes, int n_in,
                              void* d_out, int out_size, void* d_ws, size_t ws_size,
                              hipStream_t stream) {
  const float* pos    = (const float*)d_in[0];
  const float* x      = (const float*)d_in[1];
  const int*   ei     = (const int*)d_in[2];
  const int*   batch  = (const int*)d_in[3];
  const float* sb_w1  = (const float*)d_in[4];
  const float* sb_b1  = (const float*)d_in[5];
  const float* sb_w2  = (const float*)d_in[6];
  const float* sb_b2  = (const float*)d_in[7];
  const float* fb_w1  = (const float*)d_in[8];
  const float* fb_b1  = (const float*)d_in[9];
  const float* fb_w2  = (const float*)d_in[10];
  const float* fb_b2  = (const float*)d_in[11];
  const float* emb_w  = (const float*)d_in[12];
  const float* conv_kw= (const float*)d_in[13];
  const float* fib_kw = (const float*)d_in[14];
  const float* conv_b = (const float*)d_in[15];
  const float* ln_s   = (const float*)d_in[16];
  const float* ln_b   = (const float*)d_in[17];
  const float* l1_w   = (const float*)d_in[18];
  const float* l1_b   = (const float*)d_in[19];
  const float* l2_w   = (const float*)d_in[20];
  const float* l2_b   = (const float*)d_in[21];
  const float* ro_w   = (const float*)d_in[22];
  const float* ro_b   = (const float*)d_in[23];

  float* ws_f   = (float*)d_ws;
  float* g_ori  = ws_f + OFF_ORI;
  float* g_fk   = ws_f + OFF_FK;
  float* g_h    = ws_f + OFF_H;
  unsigned short* g_xnb = (unsigned short*)(ws_f + OFF_XNB);
  float* g_racc = ws_f + OFF_RACC;
  int*   row_ptr= (int*)(ws_f + OFF_RP);
  int*   cursor = (int*)(ws_f + OFF_CUR);
  int*   e0s    = (int*)(ws_f + OFF_E0S);
  float4* rel4  = (float4*)(ws_f + OFF_REL);
  unsigned short* g_wp  = (unsigned short*)(ws_f + OFF_WP);
  unsigned*       g_ckp = (unsigned*)(ws_f + OFF_CKP);
  unsigned*       kb_u  = (unsigned*)(ws_f + OFF_KB);
  float* out_f  = (float*)d_out;

  (void)hipMemsetAsync(g_racc, 0, 240000*sizeof(float), stream);
  k_setup<<<3, 256, 0, stream>>>(fb_w1, fb_b1, fb_w2, fb_b2, fib_kw, g_ori, g_fk);
  k_embed<<<512, 256, 0, stream>>>(x, emb_w, g_h);

  (void)hipMemsetAsync(cursor, 0, (N_+1)*sizeof(int), stream);
  k_count<<<(E_+255)/256, 256, 0, stream>>>(ei, cursor);
  k_scan<<<1, 256, 0, stream>>>(cursor, row_ptr);
  k_scatter<<<(E_+255)/256, 256, 0, stream>>>(pos, ei, cursor, e0s, rel4);
  k_sortbins<<<(N_+255)/256, 256, 0, stream>>>(row_ptr, e0s, rel4);
  k_pack<<<3, 256, 0, stream>>>(l1_w, l2_w, conv_kw, g_wp, g_ckp);
  k_basis_f16<<<(E_*ORI_)/256, 256, 0, stream>>>(rel4, sb_w1, sb_b1, sb_w2, sb_b2, g_ori, kb_u);
  for (int i = 0; i < 3; ++i) {
    k_aggr_f16<<<N_, 256, 0, stream>>>(kb_u, row_ptr, e0s, g_ckp + (size_t)i*2048,
                                       g_fk + i*9216, conv_b + i*64,
                                       ln_s + i*64, ln_b + i*64, g_h, g_xnb);
    k_mlp_mfma<<<256, 512, 0, stream>>>(g_xnb, g_h,
                                        g_wp + (size_t)i*32768, g_wp + (size_t)i*32768 + 16384,
                                        l1_b + i*256, l2_b + i*64,
                                        ro_w + i*128, ro_b + i*2, g_racc);
  }
  (void)hipMemsetAsync(out_f, 0, 32*sizeof(float), stream);
  k_final<<<128, 256, 0, stream>>>(g_racc, batch, g_ori, out_f);
}

// Round 12
// 930.341 us; speedup vs baseline: 1.9023x; 1.1888x over previous
//
#include <hip/hip_runtime.h>
#include <math.h>

namespace {
constexpr int N_   = 10000;
constexpr int E_   = 80000;
constexpr int ORI_ = 12;
constexpr int HC_  = 768;   // ORI*C
constexpr float EPS_ = 1e-6f;

// workspace layout (float units) — total ~172 MB (proven ws >= 187 MB)
constexpr size_t OFF_ORI  = 0;                        // 64
constexpr size_t OFF_FK   = 64;                       // 27648
constexpr size_t OFF_H    = OFF_FK + 27648;           // 7,680,000 (fp32 h)
constexpr size_t OFF_XNB  = OFF_H + 7680000;          // 3,840,000 (bf16 xn)
constexpr size_t OFF_RACC = OFF_XNB + 3840000;        // 240,000
constexpr size_t OFF_RP   = OFF_RACC + 240000;        // 10001 ints
constexpr size_t OFF_CUR  = OFF_RP + 10001;           // 10001 ints
constexpr size_t OFF_E0S  = OFF_CUR + 10001;          // 80000 ints
constexpr size_t OFF_REL  = ((OFF_E0S + 80000 + 3) / 4) * 4;   // 80000 float4
constexpr size_t OFF_WP   = ((OFF_REL + 320000 + 3) / 4) * 4;  // 3*32768 u16 (MLP)
constexpr size_t OFF_CKP  = OFF_WP + 49152;           // 3*2048 u32 f16-pairs
constexpr size_t OFF_W2F  = OFF_CKP + 6144;           // 4096 u16 basis-w2 f16 frags
constexpr size_t OFF_KB   = OFF_W2F + 2048;           // f16 kb: 960000 rows * 32 u32
constexpr size_t KB_F     = (size_t)E_ * ORI_ * 64 / 2;        // 30,720,000 f
}

typedef short bf16x8 __attribute__((ext_vector_type(8)));
typedef _Float16 f16x8 __attribute__((ext_vector_type(8)));
typedef float f32x4  __attribute__((ext_vector_type(4)));
typedef _Float16 half2v __attribute__((ext_vector_type(2)));

#if __has_builtin(__builtin_amdgcn_fdot2)
#define FDOT2(a,b,c) __builtin_amdgcn_fdot2((a),(b),(c),false)
#else
__device__ __forceinline__ float FDOT2(half2v a, half2v b, float c) {
  return c + (float)a.x*(float)b.x + (float)a.y*(float)b.y;
}
#endif

__device__ __forceinline__ float gelu_f(float x) {
  float x2 = x * x;
  float u  = x * fmaf(x2, 0.10294324f, 2.30220826f);
  float t  = __builtin_amdgcn_exp2f(u);
  float r  = __builtin_amdgcn_rcpf(t + 1.0f);
  return fmaf(-x, r, x);
}

__device__ __forceinline__ void wave_sync() {
  asm volatile("s_waitcnt lgkmcnt(0)" ::: "memory");
  __builtin_amdgcn_wave_barrier();
}

__device__ __forceinline__ float wave_sum64(float v) {
#pragma unroll
  for (int off = 32; off > 0; off >>= 1) v += __shfl_xor(v, off, 64);
  return v;
}

__device__ __forceinline__ unsigned short f2bf(float x) {
  unsigned u = __float_as_uint(x);
  unsigned r = (u + 0x7fffu + ((u >> 16) & 1u)) >> 16;  // RNE
  return (unsigned short)r;
}

__device__ __forceinline__ unsigned short f2h(float x) {
  _Float16 h = (_Float16)x;
  unsigned short u;
  __builtin_memcpy(&u, &h, 2);
  return u;
}

__device__ __forceinline__ _Float16 f2hh(float x) { return (_Float16)x; }

__device__ __forceinline__ half2v u2h2(unsigned u) {
  half2v h;
  __builtin_memcpy(&h, &u, 4);
  return h;
}

// ---------------------------------------------------------------------------
// Setup: grid=3 (one block per layer), all weights LDS-staged.
// ---------------------------------------------------------------------------
__global__ __launch_bounds__(256) void k_setup(
    const float* __restrict__ fb_w1, const float* __restrict__ fb_b1,
    const float* __restrict__ fb_w2, const float* __restrict__ fb_b2,
    const float* __restrict__ fib_kw,
    float* __restrict__ g_ori, float* __restrict__ g_fk) {
  __shared__ float s_ori[36];
  __shared__ float s_w1[192];
  __shared__ float s_b1[64], s_b2[64];
  __shared__ float s_w2[4096];
  __shared__ float s_fib[4096];
  __shared__ float s_h1[144*64];
  __shared__ float s_kb[144*64];
  int tid = threadIdx.x;
  int i = blockIdx.x;
  if (tid < 12) {
    const double PI = 3.14159265358979323846;
    double th = fmod(PI * (double)tid * (1.0 + sqrt(5.0)), 2.0 * PI);
    double ph = acos(1.0 - 2.0 * ((double)tid + 0.5) / 12.0);
    float sx = (float)(sin(ph) * cos(th));
    float sy = (float)(sin(ph) * sin(th));
    float sz = (float)cos(ph);
    s_ori[tid*3+0]=sx; s_ori[tid*3+1]=sy; s_ori[tid*3+2]=sz;
    if (i == 0) { g_ori[tid*3+0]=sx; g_ori[tid*3+1]=sy; g_ori[tid*3+2]=sz; }
  }
  for (int k = tid; k < 4096; k += 256) { s_w2[k] = fb_w2[k]; s_fib[k] = fib_kw[i*4096 + k]; }
  if (tid < 192) s_w1[tid] = fb_w1[tid];
  if (tid < 64) { s_b1[tid] = fb_b1[tid]; s_b2[tid] = fb_b2[tid]; }
  __syncthreads();
  int wid = tid >> 6, lane = tid & 63;
  for (int r = wid; r < 144; r += 4) {
    int p = r / 12, o = r % 12;
    float s = s_ori[p*3+0]*s_ori[o*3+0] + s_ori[p*3+1]*s_ori[o*3+1] + s_ori[p*3+2]*s_ori[o*3+2];
    float f1 = s, f2 = s*s, f3 = s*s*s;
    float a1 = s_b1[lane] + f1*s_w1[lane] + f2*s_w1[64+lane] + f3*s_w1[128+lane];
    s_h1[r*64+lane] = gelu_f(a1);
  }
  __syncthreads();
  for (int r = wid; r < 144; r += 4) {
    float a2 = s_b2[lane];
    for (int j = 0; j < 64; ++j) a2 += s_h1[r*64+j] * s_w2[j*64+lane];
    s_kb[r*64+lane] = gelu_f(a2);
  }
  __syncthreads();
  for (int r = wid; r < 144; r += 4) {
    float acc = 0.f;
    for (int j = 0; j < 64; ++j) acc += s_kb[r*64+j] * s_fib[j*64+lane];
    g_fk[i*9216 + r*64 + lane] = acc;
  }
}

// ---------------------------------------------------------------------------
// Embed
// ---------------------------------------------------------------------------
__global__ __launch_bounds__(256) void k_embed(
    const float* __restrict__ x, const float* __restrict__ emb_w,
    float* __restrict__ h) {
  __shared__ float s_w[16*64];
  int tid = threadIdx.x;
  for (int i = tid; i < 16*64; i += 256) s_w[i] = emb_w[i];
  __syncthreads();
  int wid = tid >> 6, lane = tid & 63;
  int nw = gridDim.x * 4;
  for (int n = blockIdx.x*4 + wid; n < N_; n += nw) {
    float acc = 0.f;
#pragma unroll
    for (int k = 0; k < 16; ++k) acc += x[n*16+k] * s_w[k*64+lane];
#pragma unroll
    for (int o = 0; o < ORI_; ++o) h[n*HC_ + o*64 + lane] = acc;
  }
}

// ---------------------------------------------------------------------------
// CSR build
// ---------------------------------------------------------------------------
__global__ __launch_bounds__(256) void k_count(const int* __restrict__ ei, int* __restrict__ cnt) {
  int e = blockIdx.x*256 + threadIdx.x;
  if (e < E_) atomicAdd(&cnt[ei[E_ + e]], 1);
}

__global__ __launch_bounds__(256) void k_scan(int* __restrict__ cnt, int* __restrict__ row_ptr) {
  __shared__ int s_sum[256];
  int tid = threadIdx.x;
  int start = tid * 40, end = min(start + 40, N_);
  int s = 0;
  for (int i = start; i < end; ++i) s += cnt[i];
  s_sum[tid] = s;
  __syncthreads();
  if (tid == 0) {
    int run = 0;
    for (int i = 0; i < 256; ++i) { int t = s_sum[i]; s_sum[i] = run; run += t; }
  }
  __syncthreads();
  int run = s_sum[tid];
  for (int i = start; i < end; ++i) { int c = cnt[i]; row_ptr[i] = run; cnt[i] = run; run += c; }
  if (tid == 0) row_ptr[N_] = E_;
}

__global__ __launch_bounds__(256) void k_scatter(
    const float* __restrict__ pos, const int* __restrict__ ei,
    int* __restrict__ cursor, int* __restrict__ e0s, float4* __restrict__ rel4) {
  int e = blockIdx.x*256 + threadIdx.x;
  if (e >= E_) return;
  int a = ei[e], b = ei[E_ + e];
  int slot = atomicAdd(&cursor[b], 1);
  float rx = pos[a*3+0]-pos[b*3+0];
  float ry = pos[a*3+1]-pos[b*3+1];
  float rz = pos[a*3+2]-pos[b*3+2];
  e0s[slot] = a;
  rel4[slot] = make_float4(rx, ry, rz, __int_as_float(e));
}

__global__ __launch_bounds__(256) void k_sortbins(
    const int* __restrict__ row_ptr, int* __restrict__ e0s, float4* __restrict__ rel4) {
  int n = blockIdx.x*256 + threadIdx.x;
  if (n >= N_) return;
  int lo = row_ptr[n], hi = row_ptr[n+1];
  for (int i = lo + 1; i < hi; ++i) {
    float4 key = rel4[i]; int kk = __float_as_int(key.w); int ke = e0s[i];
    int j = i - 1;
    while (j >= lo && __float_as_int(rel4[j].w) > kk) {
      rel4[j+1] = rel4[j]; e0s[j+1] = e0s[j]; --j;
    }
    rel4[j+1] = key; e0s[j+1] = ke;
  }
}

// ---------------------------------------------------------------------------
// Basis v2: stage1 on VALU (K=14), stage2 via f16 MFMA.
// Wave tile = 16 rows (r0..r0+15).  Thread (g,m): row r0+m, computes h1
// channels {g*8+q, 32+g*8+q} == its two A-fragments.  w2 f16 B-frags in
// VGPRs.  C-frag gelu -> f16 -> swizzled LDS -> coalesced writeout.
// ---------------------------------------------------------------------------
__global__ __launch_bounds__(256) void k_basis_v2(
    const float4* __restrict__ rel4,
    const float* __restrict__ sb_w1, const float* __restrict__ sb_b1,
    const unsigned short* __restrict__ w2f, const float* __restrict__ sb_b2,
    const float* __restrict__ g_ori, unsigned* __restrict__ kb_u) {
  __shared__ float s_w1[14*64];
  __shared__ float s_b1[64];
  __shared__ float s_b2[64];
  __shared__ float s_ori[36];
  __shared__ unsigned short s_st[4][1024];
  int tid = threadIdx.x;
  int wid = tid >> 6, lane = tid & 63;
  int g = lane >> 4, m = lane & 15;
  for (int i = tid; i < 14*64; i += 256) s_w1[i] = sb_w1[i];
  if (tid < 64) { s_b1[tid] = sb_b1[tid]; s_b2[tid] = sb_b2[tid]; }
  if (tid < 36) s_ori[tid] = g_ori[tid];
  f16x8 wf[8];
#pragma unroll
  for (int fi = 0; fi < 8; ++fi) wf[fi] = *(const f16x8*)(w2f + fi*512 + lane*8);
  float b2v[4];
  __syncthreads();
#pragma unroll
  for (int ct = 0; ct < 4; ++ct) b2v[ct] = s_b2[ct*16 + m];
  unsigned short* st = s_st[wid];
  unsigned short* kb16 = (unsigned short*)kb_u;
  for (int t = blockIdx.x*4 + wid; t < 60000; t += 15000) {
    int r0 = t * 16;
    int r = r0 + m;
    int s = r / 12, o = r - s*12;
    float4 rv = rel4[s];
    float rx = rv.x, ry = rv.y, rz = rv.z;
    float ox = s_ori[o*3+0], oy = s_ori[o*3+1], oz = s_ori[o*3+2];
    float i1 = rx*ox + ry*oy + rz*oz;
    float px = rx - i1*ox, py = ry - i1*oy, pz = rz - i1*oz;
    float i2 = sqrtf(px*px + py*py + pz*pz);
    float f[14];
    f[0]=i1; f[1]=i2; f[2]=i1*i1; f[3]=i1*i2; f[4]=i2*i1; f[5]=i2*i2;
    f[6]=f[2]*i1; f[7]=f[2]*i2; f[8]=f[3]*i1; f[9]=f[3]*i2;
    f[10]=f[4]*i1; f[11]=f[4]*i2; f[12]=f[5]*i1; f[13]=f[5]*i2;
    // stage1: 16 h1 channels: {g*8+q} (half 0) and {32+g*8+q} (half 1)
    f16x8 a0, a1;
#pragma unroll
    for (int hh = 0; hh < 2; ++hh) {
      int bc = hh*32 + g*8;
      float4 ac0 = *(const float4*)&s_b1[bc];
      float4 ac1 = *(const float4*)&s_b1[bc+4];
#pragma unroll
      for (int p = 0; p < 14; ++p) {
        float fp = f[p];
        float4 w0 = *(const float4*)&s_w1[p*64 + bc];
        float4 w1v = *(const float4*)&s_w1[p*64 + bc + 4];
        ac0.x += fp*w0.x; ac0.y += fp*w0.y; ac0.z += fp*w0.z; ac0.w += fp*w0.w;
        ac1.x += fp*w1v.x; ac1.y += fp*w1v.y; ac1.z += fp*w1v.z; ac1.w += fp*w1v.w;
      }
      f16x8& dst = hh ? a1 : a0;
      dst[0] = f2hh(gelu_f(ac0.x)); dst[1] = f2hh(gelu_f(ac0.y));
      dst[2] = f2hh(gelu_f(ac0.z)); dst[3] = f2hh(gelu_f(ac0.w));
      dst[4] = f2hh(gelu_f(ac1.x)); dst[5] = f2hh(gelu_f(ac1.y));
      dst[6] = f2hh(gelu_f(ac1.z)); dst[7] = f2hh(gelu_f(ac1.w));
    }
    // stage2: 8 MFMAs -> out[16][64]
    f32x4 acc[4];
#pragma unroll
    for (int ct = 0; ct < 4; ++ct) {
      acc[ct] = (f32x4){0.f, 0.f, 0.f, 0.f};
      acc[ct] = __builtin_amdgcn_mfma_f32_16x16x32_f16(a0, wf[ct*2+0], acc[ct], 0, 0, 0);
      acc[ct] = __builtin_amdgcn_mfma_f32_16x16x32_f16(a1, wf[ct*2+1], acc[ct], 0, 0, 0);
    }
    // epilogue: gelu -> f16 -> swizzled LDS
#pragma unroll
    for (int ct = 0; ct < 4; ++ct) {
#pragma unroll
      for (int reg = 0; reg < 4; ++reg) {
        int row = 4*g + reg;
        int col = (ct*16 + m) ^ (g << 4);
        st[row*64 + col] = f2h(gelu_f(acc[ct][reg] + b2v[ct]));
      }
    }
    wave_sync();
#pragma unroll
    for (int p2 = 0; p2 < 2; ++p2) {
      int row = p2*8 + (lane >> 3);
      int cb  = (lane & 7) * 8;
      int sc  = cb ^ (((row >> 2) & 3) << 4);
      uint4 v = *(const uint4*)(st + row*64 + sc);
      *(uint4*)(kb16 + (size_t)r0*64 + p2*512 + lane*8) = v;
    }
    wave_sync();
  }
}

// ---------------------------------------------------------------------------
// Pack weights (once): MLP w1/w2 bf16 MFMA fragments + conv_kw f16-pairs
// + basis sb_w2 f16 B-fragments (block 0 only).
// ---------------------------------------------------------------------------
__global__ __launch_bounds__(256) void k_pack(
    const float* __restrict__ l1_w, const float* __restrict__ l2_w,
    const float* __restrict__ conv_kw, const float* __restrict__ sb_w2,
    unsigned short* __restrict__ wp, unsigned* __restrict__ ckp2,
    unsigned short* __restrict__ w2f) {
  int i = blockIdx.x;
  unsigned short* w1p = wp + (size_t)i*32768;
  unsigned short* w2p = w1p + 16384;
  const float* w1 = l1_w + i*16384;
  const float* w2 = l2_w + i*16384;
  for (int k = threadIdx.x; k < 16384; k += 256) {
    int c = k >> 8, j = k & 255;          // w1[c][j]
    int jt = j >> 4, hh = c >> 5, gg = (c >> 3) & 3, kp = c & 7;
    int l = gg*16 + (j & 15);
    w1p[jt*1024 + hh*512 + l*8 + kp] = f2bf(w1[k]);
    int j2 = k >> 6, c2 = k & 63;         // w2[j2][c2]
    int ct = c2 >> 4, ks = j2 >> 5, g2 = (j2 >> 3) & 3, kp2 = j2 & 7;
    int l2 = g2*16 + (c2 & 15);
    w2p[(ct*8+ks)*512 + l2*8 + kp2] = f2bf(w2[k]);
  }
  const float* ck = conv_kw + i*4096;
  unsigned* cko = ckp2 + (size_t)i*2048;
  for (int idx = threadIdx.x; idx < 2048; idx += 256) {
    int p = idx >> 6, c = idx & 63;
    cko[idx] = (unsigned)f2h(ck[(2*p)*64 + c]) | ((unsigned)f2h(ck[(2*p+1)*64 + c]) << 16);
  }
  if (i == 0) {
    for (int idx = threadIdx.x; idx < 4096; idx += 256) {
      int fi = idx >> 9, l = (idx >> 3) & 63, kp = idx & 7;
      int ct = fi >> 1, ks = fi & 1, g = l >> 4, m = l & 15;
      w2f[idx] = f2h(sb_w2[(ks*32 + g*8 + kp)*64 + ct*16 + m]);
    }
  }
}

// ---------------------------------------------------------------------------
// Aggregation (fdot2 streaming) + conv-mix + LayerNorm -> bf16 xn.
// ---------------------------------------------------------------------------
__global__ __launch_bounds__(256) void k_aggr_f16(
    const unsigned* __restrict__ kb_u, const int* __restrict__ row_ptr,
    const int* __restrict__ e0s, const unsigned* __restrict__ ckp2,
    const float* __restrict__ g_fk_i, const float* __restrict__ conv_b,
    const float* __restrict__ ln_s, const float* __restrict__ ln_b,
    const float* __restrict__ h, unsigned short* __restrict__ xnb) {
  __shared__ float s_fk[9216];
  __shared__ float s_x1[768];
  __shared__ float s_cb[64], s_ls[64], s_lb[64];
  __shared__ unsigned s_row[4][2][32];
  int tid = threadIdx.x;
  int wid = tid >> 6, lane = tid & 63;
  for (int i = tid; i < 9216; i += 256) s_fk[i] = g_fk_i[i];
  if (tid < 64) { s_cb[tid]=conv_b[tid]; s_ls[tid]=ln_s[tid]; s_lb[tid]=ln_b[tid]; }
  half2v ckreg[32];
#pragma unroll
  for (int p = 0; p < 32; ++p) ckreg[p] = u2h2(ckp2[p*64 + lane]);
  __syncthreads();
  int n = blockIdx.x;
  int lo = row_ptr[n], hi = row_ptr[n+1];
  for (int o = wid; o < 12; o += 4) {
    float acc = 0.f;
    if (lo < hi) {
      unsigned kn = 0; float hn;
      if (lane < 32) kn = kb_u[(size_t)(lo*12 + o)*32 + lane];
      hn = h[(size_t)e0s[lo]*HC_ + o*64 + lane];
      int buf = 0;
      for (int s = lo; s < hi; ++s) {
        unsigned kcur = kn; float hcur = hn;
        if (s + 1 < hi) {
          if (lane < 32) kn = kb_u[(size_t)((s+1)*12 + o)*32 + lane];
          hn = h[(size_t)e0s[s+1]*HC_ + o*64 + lane];
        }
        if (lane < 32) s_row[wid][buf][lane] = kcur;
        wave_sync();
        float kc = 0.f;
        const uint4* rp = (const uint4*)s_row[wid][buf];
#pragma unroll
        for (int g = 0; g < 8; ++g) {
          uint4 v = rp[g];
          kc = FDOT2(u2h2(v.x), ckreg[g*4+0], kc);
          kc = FDOT2(u2h2(v.y), ckreg[g*4+1], kc);
          kc = FDOT2(u2h2(v.z), ckreg[g*4+2], kc);
          kc = FDOT2(u2h2(v.w), ckreg[g*4+3], kc);
        }
        acc += hcur * kc;
        buf ^= 1;
      }
    }
    s_x1[o*64 + lane] = acc;
  }
  __syncthreads();
  for (int p = wid; p < 12; p += 4) {
    float a = 0.f;
#pragma unroll
    for (int o = 0; o < 12; ++o) a += s_x1[o*64+lane] * s_fk[(p*12+o)*64 + lane];
    a = a * (1.0f/12.0f) + s_cb[lane];
    float s1 = wave_sum64(a);
    float s2 = wave_sum64(a*a);
    float mu = s1 * (1.0f/64.0f);
    float var = s2 * (1.0f/64.0f) - mu*mu;
    float v = (a - mu) * rsqrtf(var + EPS_) * s_ls[lane] + s_lb[lane];
    xnb[(size_t)n*HC_ + p*64 + lane] = f2bf(v);
  }
}

// ---------------------------------------------------------------------------
// Node MLP via MFMA (bf16)
// ---------------------------------------------------------------------------
__global__ __launch_bounds__(512) void k_mlp_mfma(
    const unsigned short* __restrict__ xnb, float* __restrict__ h,
    const unsigned short* __restrict__ w1p, const unsigned short* __restrict__ w2p,
    const float* __restrict__ l1_b, const float* __restrict__ l2_b,
    const float* __restrict__ ro_w, const float* __restrict__ ro_b,
    float* __restrict__ racc) {
  __shared__ unsigned short s_w1p[16384];
  __shared__ unsigned short s_w2p[16384];
  __shared__ float s_b1[256];
  __shared__ float s_b2[64];
  __shared__ float s_ro[128];
  __shared__ unsigned short s_hm[8][16*272];
  int tid = threadIdx.x;
  {
    const uint4* a4 = (const uint4*)w1p;  uint4* d4 = (uint4*)s_w1p;
    const uint4* b4 = (const uint4*)w2p;  uint4* e4 = (uint4*)s_w2p;
    for (int k = tid; k < 2048; k += 512) { d4[k] = a4[k]; e4[k] = b4[k]; }
  }
  if (tid < 256) s_b1[tid] = l1_b[tid];
  if (tid < 64)  s_b2[tid] = l2_b[tid];
  if (tid < 128) s_ro[tid] = ro_w[tid];
  __syncthreads();
  int wid = tid >> 6, lane = tid & 63;
  int g = lane >> 4, m = lane & 15;
  float rb0 = ro_b[0], rb1 = ro_b[1];
  float b2v[4], rw0[4], rw1[4];
#pragma unroll
  for (int ct = 0; ct < 4; ++ct) {
    b2v[ct] = s_b2[ct*16 + m];
    rw0[ct] = s_ro[(ct*16+m)*2+0];
    rw1[ct] = s_ro[(ct*16+m)*2+1];
  }
  unsigned short* hm = s_hm[wid];
  int nwg = gridDim.x * 8;
  for (int rg = blockIdx.x*8 + wid; rg < 7500; rg += nwg) {
    int r0 = rg * 16;
    bf16x8 xb0 = *(const bf16x8*)(xnb + (size_t)(r0 + m)*64 + g*8);
    bf16x8 xb1 = *(const bf16x8*)(xnb + (size_t)(r0 + m)*64 + 32 + g*8);
    wave_sync();
#pragma unroll 4
    for (int jt = 0; jt < 16; ++jt) {
      bf16x8 a0 = *(const bf16x8*)(s_w1p + jt*1024 + lane*8);
      bf16x8 a1 = *(const bf16x8*)(s_w1p + jt*1024 + 512 + lane*8);
      f32x4 acc = {0.f, 0.f, 0.f, 0.f};
      acc = __builtin_amdgcn_mfma_f32_16x16x32_bf16(a0, xb0, acc, 0, 0, 0);
      acc = __builtin_amdgcn_mfma_f32_16x16x32_bf16(a1, xb1, acc, 0, 0, 0);
      float4 b1v = *(const float4*)&s_b1[jt*16 + g*4];
      float g0 = gelu_f(acc[0] + b1v.x);
      float g1 = gelu_f(acc[1] + b1v.y);
      float g2 = gelu_f(acc[2] + b1v.z);
      float g3 = gelu_f(acc[3] + b1v.w);
      unsigned wa = (unsigned)f2bf(g0) | ((unsigned)f2bf(g1) << 16);
      unsigned wb = (unsigned)f2bf(g2) | ((unsigned)f2bf(g3) << 16);
      *(uint2*)(hm + m*272 + jt*16 + g*4) = make_uint2(wa, wb);
    }
    wave_sync();
    f32x4 acc2[4];
#pragma unroll
    for (int ct = 0; ct < 4; ++ct) acc2[ct] = (f32x4){0.f, 0.f, 0.f, 0.f};
#pragma unroll
    for (int ks = 0; ks < 8; ++ks) {
      bf16x8 a2 = *(const bf16x8*)(hm + m*272 + ks*32 + g*8);
#pragma unroll
      for (int ct = 0; ct < 4; ++ct) {
        bf16x8 bf = *(const bf16x8*)(s_w2p + (ct*8+ks)*512 + lane*8);
        acc2[ct] = __builtin_amdgcn_mfma_f32_16x16x32_bf16(a2, bf, acc2[ct], 0, 0, 0);
      }
    }
    wave_sync();
#pragma unroll
    for (int reg = 0; reg < 4; ++reg) {
      int r = r0 + 4*g + reg;
      float v0 = 0.f, v1 = 0.f;
#pragma unroll
      for (int ct = 0; ct < 4; ++ct) {
        size_t idx = (size_t)r*64 + ct*16 + m;
        float hnew = acc2[ct][reg] + b2v[ct] + h[idx];
        h[idx] = hnew;
        v0 += hnew * rw0[ct];
        v1 += hnew * rw1[ct];
      }
#pragma unroll
      for (int off = 8; off > 0; off >>= 1) {
        v0 += __shfl_xor(v0, off, 16);
        v1 += __shfl_xor(v1, off, 16);
      }
      if (m == 0) {
        racc[r*2+0] += v0 + rb0;
        racc[r*2+1] += v1 + rb1;
      }
    }
  }
}

// ---------------------------------------------------------------------------
// Final segment-sum
// ---------------------------------------------------------------------------
__global__ __launch_bounds__(256) void k_final(
    const float* __restrict__ racc, const int* __restrict__ batch,
    const float* __restrict__ g_ori, float* __restrict__ out) {
  __shared__ float s_part[32];
  __shared__ float s_ori[36];
  int tid = threadIdx.x;
  if (tid < 32) s_part[tid] = 0.f;
  if (tid < 36) s_ori[tid] = g_ori[tid];
  __syncthreads();
  const float sc = 1.0f / 36.0f;
  for (int n = blockIdx.x*256 + tid; n < N_; n += gridDim.x*256) {
    int bt = batch[n];
    float ss = 0.f, v0 = 0.f, v1 = 0.f, v2 = 0.f;
#pragma unroll
    for (int o = 0; o < 12; ++o) {
      float r0 = racc[n*24 + o*2 + 0];
      float r1 = racc[n*24 + o*2 + 1];
      ss += r0;
      v0 += r1 * s_ori[o*3+0];
      v1 += r1 * s_ori[o*3+1];
      v2 += r1 * s_ori[o*3+2];
    }
    atomicAdd(&s_part[bt], ss*sc);
    atomicAdd(&s_part[8 + bt*3 + 0], v0*sc);
    atomicAdd(&s_part[8 + bt*3 + 1], v1*sc);
    atomicAdd(&s_part[8 + bt*3 + 2], v2*sc);
  }
  __syncthreads();
  if (tid < 32) atomicAdd(&out[tid], s_part[tid]);
}

extern "C" void kernel_launch(void* const* d_in, const int* in_sizes, int n_in,
                              void* d_out, int out_size, void* d_ws, size_t ws_size,
                              hipStream_t stream) {
  const float* pos    = (const float*)d_in[0];
  const float* x      = (const float*)d_in[1];
  const int*   ei     = (const int*)d_in[2];
  const int*   batch  = (const int*)d_in[3];
  const float* sb_w1  = (const float*)d_in[4];
  const float* sb_b1  = (const float*)d_in[5];
  const float* sb_w2  = (const float*)d_in[6];
  const float* sb_b2  = (const float*)d_in[7];
  const float* fb_w1  = (const float*)d_in[8];
  const float* fb_b1  = (const float*)d_in[9];
  const float* fb_w2  = (const float*)d_in[10];
  const float* fb_b2  = (const float*)d_in[11];
  const float* emb_w  = (const float*)d_in[12];
  const float* conv_kw= (const float*)d_in[13];
  const float* fib_kw = (const float*)d_in[14];
  const float* conv_b = (const float*)d_in[15];
  const float* ln_s   = (const float*)d_in[16];
  const float* ln_b   = (const float*)d_in[17];
  const float* l1_w   = (const float*)d_in[18];
  const float* l1_b   = (const float*)d_in[19];
  const float* l2_w   = (const float*)d_in[20];
  const float* l2_b   = (const float*)d_in[21];
  const float* ro_w   = (const float*)d_in[22];
  const float* ro_b   = (const float*)d_in[23];

  float* ws_f   = (float*)d_ws;
  float* g_ori  = ws_f + OFF_ORI;
  float* g_fk   = ws_f + OFF_FK;
  float* g_h    = ws_f + OFF_H;
  unsigned short* g_xnb = (unsigned short*)(ws_f + OFF_XNB);
  float* g_racc = ws_f + OFF_RACC;
  int*   row_ptr= (int*)(ws_f + OFF_RP);
  int*   cursor = (int*)(ws_f + OFF_CUR);
  int*   e0s    = (int*)(ws_f + OFF_E0S);
  float4* rel4  = (float4*)(ws_f + OFF_REL);
  unsigned short* g_wp  = (unsigned short*)(ws_f + OFF_WP);
  unsigned*       g_ckp = (unsigned*)(ws_f + OFF_CKP);
  unsigned short* g_w2f = (unsigned short*)(ws_f + OFF_W2F);
  unsigned*       kb_u  = (unsigned*)(ws_f + OFF_KB);
  float* out_f  = (float*)d_out;

  (void)hipMemsetAsync(g_racc, 0, 240000*sizeof(float), stream);
  k_setup<<<3, 256, 0, stream>>>(fb_w1, fb_b1, fb_w2, fb_b2, fib_kw, g_ori, g_fk);
  k_embed<<<512, 256, 0, stream>>>(x, emb_w, g_h);

  (void)hipMemsetAsync(cursor, 0, (N_+1)*sizeof(int), stream);
  k_count<<<(E_+255)/256, 256, 0, stream>>>(ei, cursor);
  k_scan<<<1, 256, 0, stream>>>(cursor, row_ptr);
  k_scatter<<<(E_+255)/256, 256, 0, stream>>>(pos, ei, cursor, e0s, rel4);
  k_sortbins<<<(N_+255)/256, 256, 0, stream>>>(row_ptr, e0s, rel4);
  k_pack<<<3, 256, 0, stream>>>(l1_w, l2_w, conv_kw, sb_w2, g_wp, g_ckp, g_w2f);
  k_basis_v2<<<3750, 256, 0, stream>>>(rel4, sb_w1, sb_b1, g_w2f, sb_b2, g_ori, kb_u);
  for (int i = 0; i < 3; ++i) {
    k_aggr_f16<<<N_, 256, 0, stream>>>(kb_u, row_ptr, e0s, g_ckp + (size_t)i*2048,
                                       g_fk + i*9216, conv_b + i*64,
                                       ln_s + i*64, ln_b + i*64, g_h, g_xnb);
    k_mlp_mfma<<<256, 512, 0, stream>>>(g_xnb, g_h,
                                        g_wp + (size_t)i*32768, g_wp + (size_t)i*32768 + 16384,
                                        l1_b + i*256, l2_b + i*64,
                                        ro_w + i*128, ro_b + i*2, g_racc);
  }
  (void)hipMemsetAsync(out_f, 0, 32*sizeof(float), stream);
  k_final<<<128, 256, 0, stream>>>(g_racc, batch, g_ori, out_f);
}

// Round 13
// 727.659 us; speedup vs baseline: 2.4322x; 1.2785x over previous
//
#include <hip/hip_runtime.h>
#include <math.h>

namespace {
constexpr int N_   = 10000;
constexpr int E_   = 80000;
constexpr int ORI_ = 12;
constexpr int HC_  = 768;   // ORI*C
constexpr float EPS_ = 1e-6f;

// workspace layout (float units) — total ~172 MB (proven ws >= 187 MB)
constexpr size_t OFF_ORI  = 0;                        // 64
constexpr size_t OFF_FK   = 64;                       // 27648
constexpr size_t OFF_H    = OFF_FK + 27648;           // 7,680,000 (fp32 h)
constexpr size_t OFF_XNB  = OFF_H + 7680000;          // 3,840,000 (bf16 xn)
constexpr size_t OFF_RACC = OFF_XNB + 3840000;        // 240,000
constexpr size_t OFF_RP   = OFF_RACC + 240000;        // 10001 ints
constexpr size_t OFF_CUR  = OFF_RP + 10001;           // 10001 ints
constexpr size_t OFF_E0S  = OFF_CUR + 10001;          // 80000 ints
constexpr size_t OFF_REL  = ((OFF_E0S + 80000 + 3) / 4) * 4;   // 80000 float4
constexpr size_t OFF_WP   = ((OFF_REL + 320000 + 3) / 4) * 4;  // 3*32768 u16 (MLP)
constexpr size_t OFF_CKP  = OFF_WP + 49152;           // 3*2048 u32 f16-pairs
constexpr size_t OFF_W2F  = OFF_CKP + 6144;           // 4096 u16 basis-w2 f16 frags
constexpr size_t OFF_KB   = OFF_W2F + 2048;           // f16 kb: 960000 rows * 32 u32
constexpr size_t KB_F     = (size_t)E_ * ORI_ * 64 / 2;        // 30,720,000 f
}

typedef short bf16x8 __attribute__((ext_vector_type(8)));
typedef _Float16 f16x8 __attribute__((ext_vector_type(8)));
typedef float f32x4  __attribute__((ext_vector_type(4)));
typedef _Float16 half2v __attribute__((ext_vector_type(2)));

#if __has_builtin(__builtin_amdgcn_fdot2)
#define FDOT2(a,b,c) __builtin_amdgcn_fdot2((a),(b),(c),false)
#else
__device__ __forceinline__ float FDOT2(half2v a, half2v b, float c) {
  return c + (float)a.x*(float)b.x + (float)a.y*(float)b.y;
}
#endif

__device__ __forceinline__ float gelu_f(float x) {
  float x2 = x * x;
  float u  = x * fmaf(x2, 0.10294324f, 2.30220826f);
  float t  = __builtin_amdgcn_exp2f(u);
  float r  = __builtin_amdgcn_rcpf(t + 1.0f);
  return fmaf(-x, r, x);
}

__device__ __forceinline__ void wave_sync() {
  asm volatile("s_waitcnt lgkmcnt(0)" ::: "memory");
  __builtin_amdgcn_wave_barrier();
}

__device__ __forceinline__ float wave_sum64(float v) {
#pragma unroll
  for (int off = 32; off > 0; off >>= 1) v += __shfl_xor(v, off, 64);
  return v;
}

__device__ __forceinline__ unsigned short f2bf(float x) {
  unsigned u = __float_as_uint(x);
  unsigned r = (u + 0x7fffu + ((u >> 16) & 1u)) >> 16;  // RNE
  return (unsigned short)r;
}

__device__ __forceinline__ unsigned short f2h(float x) {
  _Float16 h = (_Float16)x;
  unsigned short u;
  __builtin_memcpy(&u, &h, 2);
  return u;
}

__device__ __forceinline__ float h2f(unsigned short u) {
  _Float16 h;
  __builtin_memcpy(&h, &u, 2);
  return (float)h;
}

__device__ __forceinline__ _Float16 f2hh(float x) { return (_Float16)x; }

__device__ __forceinline__ half2v u2h2(unsigned u) {
  half2v h;
  __builtin_memcpy(&h, &u, 4);
  return h;
}

// ---------------------------------------------------------------------------
// Setup: grid=3 (one block per layer), all weights LDS-staged.
// ---------------------------------------------------------------------------
__global__ __launch_bounds__(256) void k_setup(
    const float* __restrict__ fb_w1, const float* __restrict__ fb_b1,
    const float* __restrict__ fb_w2, const float* __restrict__ fb_b2,
    const float* __restrict__ fib_kw,
    float* __restrict__ g_ori, float* __restrict__ g_fk) {
  __shared__ float s_ori[36];
  __shared__ float s_w1[192];
  __shared__ float s_b1[64], s_b2[64];
  __shared__ float s_w2[4096];
  __shared__ float s_fib[4096];
  __shared__ float s_h1[144*64];
  __shared__ float s_kb[144*64];
  int tid = threadIdx.x;
  int i = blockIdx.x;
  if (tid < 12) {
    const double PI = 3.14159265358979323846;
    double th = fmod(PI * (double)tid * (1.0 + sqrt(5.0)), 2.0 * PI);
    double ph = acos(1.0 - 2.0 * ((double)tid + 0.5) / 12.0);
    float sx = (float)(sin(ph) * cos(th));
    float sy = (float)(sin(ph) * sin(th));
    float sz = (float)cos(ph);
    s_ori[tid*3+0]=sx; s_ori[tid*3+1]=sy; s_ori[tid*3+2]=sz;
    if (i == 0) { g_ori[tid*3+0]=sx; g_ori[tid*3+1]=sy; g_ori[tid*3+2]=sz; }
  }
  for (int k = tid; k < 4096; k += 256) { s_w2[k] = fb_w2[k]; s_fib[k] = fib_kw[i*4096 + k]; }
  if (tid < 192) s_w1[tid] = fb_w1[tid];
  if (tid < 64) { s_b1[tid] = fb_b1[tid]; s_b2[tid] = fb_b2[tid]; }
  __syncthreads();
  int wid = tid >> 6, lane = tid & 63;
  for (int r = wid; r < 144; r += 4) {
    int p = r / 12, o = r % 12;
    float s = s_ori[p*3+0]*s_ori[o*3+0] + s_ori[p*3+1]*s_ori[o*3+1] + s_ori[p*3+2]*s_ori[o*3+2];
    float f1 = s, f2 = s*s, f3 = s*s*s;
    float a1 = s_b1[lane] + f1*s_w1[lane] + f2*s_w1[64+lane] + f3*s_w1[128+lane];
    s_h1[r*64+lane] = gelu_f(a1);
  }
  __syncthreads();
  for (int r = wid; r < 144; r += 4) {
    float a2 = s_b2[lane];
    for (int j = 0; j < 64; ++j) a2 += s_h1[r*64+j] * s_w2[j*64+lane];
    s_kb[r*64+lane] = gelu_f(a2);
  }
  __syncthreads();
  for (int r = wid; r < 144; r += 4) {
    float acc = 0.f;
    for (int j = 0; j < 64; ++j) acc += s_kb[r*64+j] * s_fib[j*64+lane];
    g_fk[i*9216 + r*64 + lane] = acc;
  }
}

// ---------------------------------------------------------------------------
// Embed
// ---------------------------------------------------------------------------
__global__ __launch_bounds__(256) void k_embed(
    const float* __restrict__ x, const float* __restrict__ emb_w,
    float* __restrict__ h) {
  __shared__ float s_w[16*64];
  int tid = threadIdx.x;
  for (int i = tid; i < 16*64; i += 256) s_w[i] = emb_w[i];
  __syncthreads();
  int wid = tid >> 6, lane = tid & 63;
  int nw = gridDim.x * 4;
  for (int n = blockIdx.x*4 + wid; n < N_; n += nw) {
    float acc = 0.f;
#pragma unroll
    for (int k = 0; k < 16; ++k) acc += x[n*16+k] * s_w[k*64+lane];
#pragma unroll
    for (int o = 0; o < ORI_; ++o) h[n*HC_ + o*64 + lane] = acc;
  }
}

// ---------------------------------------------------------------------------
// CSR build
// ---------------------------------------------------------------------------
__global__ __launch_bounds__(256) void k_count(const int* __restrict__ ei, int* __restrict__ cnt) {
  int e = blockIdx.x*256 + threadIdx.x;
  if (e < E_) atomicAdd(&cnt[ei[E_ + e]], 1);
}

__global__ __launch_bounds__(256) void k_scan(int* __restrict__ cnt, int* __restrict__ row_ptr) {
  __shared__ int s_sum[256];
  int tid = threadIdx.x;
  int start = tid * 40, end = min(start + 40, N_);
  int s = 0;
  for (int i = start; i < end; ++i) s += cnt[i];
  s_sum[tid] = s;
  __syncthreads();
  if (tid == 0) {
    int run = 0;
    for (int i = 0; i < 256; ++i) { int t = s_sum[i]; s_sum[i] = run; run += t; }
  }
  __syncthreads();
  int run = s_sum[tid];
  for (int i = start; i < end; ++i) { int c = cnt[i]; row_ptr[i] = run; cnt[i] = run; run += c; }
  if (tid == 0) row_ptr[N_] = E_;
}

__global__ __launch_bounds__(256) void k_scatter(
    const float* __restrict__ pos, const int* __restrict__ ei,
    int* __restrict__ cursor, int* __restrict__ e0s, float4* __restrict__ rel4) {
  int e = blockIdx.x*256 + threadIdx.x;
  if (e >= E_) return;
  int a = ei[e], b = ei[E_ + e];
  int slot = atomicAdd(&cursor[b], 1);
  float rx = pos[a*3+0]-pos[b*3+0];
  float ry = pos[a*3+1]-pos[b*3+1];
  float rz = pos[a*3+2]-pos[b*3+2];
  e0s[slot] = a;
  rel4[slot] = make_float4(rx, ry, rz, __int_as_float(e));
}

__global__ __launch_bounds__(256) void k_sortbins(
    const int* __restrict__ row_ptr, int* __restrict__ e0s, float4* __restrict__ rel4) {
  int n = blockIdx.x*256 + threadIdx.x;
  if (n >= N_) return;
  int lo = row_ptr[n], hi = row_ptr[n+1];
  for (int i = lo + 1; i < hi; ++i) {
    float4 key = rel4[i]; int kk = __float_as_int(key.w); int ke = e0s[i];
    int j = i - 1;
    while (j >= lo && __float_as_int(rel4[j].w) > kk) {
      rel4[j+1] = rel4[j]; e0s[j+1] = e0s[j]; --j;
    }
    rel4[j+1] = key; e0s[j+1] = ke;
  }
}

// ---------------------------------------------------------------------------
// Basis v2: stage1 on VALU (K=14), stage2 via f16 MFMA.
// ---------------------------------------------------------------------------
__global__ __launch_bounds__(256) void k_basis_v2(
    const float4* __restrict__ rel4,
    const float* __restrict__ sb_w1, const float* __restrict__ sb_b1,
    const unsigned short* __restrict__ w2f, const float* __restrict__ sb_b2,
    const float* __restrict__ g_ori, unsigned* __restrict__ kb_u) {
  __shared__ float s_w1[14*64];
  __shared__ float s_b1[64];
  __shared__ float s_b2[64];
  __shared__ float s_ori[36];
  __shared__ unsigned short s_st[4][1024];
  int tid = threadIdx.x;
  int wid = tid >> 6, lane = tid & 63;
  int g = lane >> 4, m = lane & 15;
  for (int i = tid; i < 14*64; i += 256) s_w1[i] = sb_w1[i];
  if (tid < 64) { s_b1[tid] = sb_b1[tid]; s_b2[tid] = sb_b2[tid]; }
  if (tid < 36) s_ori[tid] = g_ori[tid];
  f16x8 wf[8];
#pragma unroll
  for (int fi = 0; fi < 8; ++fi) wf[fi] = *(const f16x8*)(w2f + fi*512 + lane*8);
  float b2v[4];
  __syncthreads();
#pragma unroll
  for (int ct = 0; ct < 4; ++ct) b2v[ct] = s_b2[ct*16 + m];
  unsigned short* st = s_st[wid];
  unsigned short* kb16 = (unsigned short*)kb_u;
  for (int t = blockIdx.x*4 + wid; t < 60000; t += 15000) {
    int r0 = t * 16;
    int r = r0 + m;
    int s = r / 12, o = r - s*12;
    float4 rv = rel4[s];
    float rx = rv.x, ry = rv.y, rz = rv.z;
    float ox = s_ori[o*3+0], oy = s_ori[o*3+1], oz = s_ori[o*3+2];
    float i1 = rx*ox + ry*oy + rz*oz;
    float px = rx - i1*ox, py = ry - i1*oy, pz = rz - i1*oz;
    float i2 = sqrtf(px*px + py*py + pz*pz);
    float f[14];
    f[0]=i1; f[1]=i2; f[2]=i1*i1; f[3]=i1*i2; f[4]=i2*i1; f[5]=i2*i2;
    f[6]=f[2]*i1; f[7]=f[2]*i2; f[8]=f[3]*i1; f[9]=f[3]*i2;
    f[10]=f[4]*i1; f[11]=f[4]*i2; f[12]=f[5]*i1; f[13]=f[5]*i2;
    f16x8 a0, a1;
#pragma unroll
    for (int hh = 0; hh < 2; ++hh) {
      int bc = hh*32 + g*8;
      float4 ac0 = *(const float4*)&s_b1[bc];
      float4 ac1 = *(const float4*)&s_b1[bc+4];
#pragma unroll
      for (int p = 0; p < 14; ++p) {
        float fp = f[p];
        float4 w0 = *(const float4*)&s_w1[p*64 + bc];
        float4 w1v = *(const float4*)&s_w1[p*64 + bc + 4];
        ac0.x += fp*w0.x; ac0.y += fp*w0.y; ac0.z += fp*w0.z; ac0.w += fp*w0.w;
        ac1.x += fp*w1v.x; ac1.y += fp*w1v.y; ac1.z += fp*w1v.z; ac1.w += fp*w1v.w;
      }
      f16x8& dst = hh ? a1 : a0;
      dst[0] = f2hh(gelu_f(ac0.x)); dst[1] = f2hh(gelu_f(ac0.y));
      dst[2] = f2hh(gelu_f(ac0.z)); dst[3] = f2hh(gelu_f(ac0.w));
      dst[4] = f2hh(gelu_f(ac1.x)); dst[5] = f2hh(gelu_f(ac1.y));
      dst[6] = f2hh(gelu_f(ac1.z)); dst[7] = f2hh(gelu_f(ac1.w));
    }
    f32x4 acc[4];
#pragma unroll
    for (int ct = 0; ct < 4; ++ct) {
      acc[ct] = (f32x4){0.f, 0.f, 0.f, 0.f};
      acc[ct] = __builtin_amdgcn_mfma_f32_16x16x32_f16(a0, wf[ct*2+0], acc[ct], 0, 0, 0);
      acc[ct] = __builtin_amdgcn_mfma_f32_16x16x32_f16(a1, wf[ct*2+1], acc[ct], 0, 0, 0);
    }
#pragma unroll
    for (int ct = 0; ct < 4; ++ct) {
#pragma unroll
      for (int reg = 0; reg < 4; ++reg) {
        int row = 4*g + reg;
        int col = (ct*16 + m) ^ (g << 4);
        st[row*64 + col] = f2h(gelu_f(acc[ct][reg] + b2v[ct]));
      }
    }
    wave_sync();
#pragma unroll
    for (int p2 = 0; p2 < 2; ++p2) {
      int row = p2*8 + (lane >> 3);
      int cb  = (lane & 7) * 8;
      int sc  = cb ^ (((row >> 2) & 3) << 4);
      uint4 v = *(const uint4*)(st + row*64 + sc);
      *(uint4*)(kb16 + (size_t)r0*64 + p2*512 + lane*8) = v;
    }
    wave_sync();
  }
}

// ---------------------------------------------------------------------------
// Pack weights (once)
// ---------------------------------------------------------------------------
__global__ __launch_bounds__(256) void k_pack(
    const float* __restrict__ l1_w, const float* __restrict__ l2_w,
    const float* __restrict__ conv_kw, const float* __restrict__ sb_w2,
    unsigned short* __restrict__ wp, unsigned* __restrict__ ckp2,
    unsigned short* __restrict__ w2f) {
  int i = blockIdx.x;
  unsigned short* w1p = wp + (size_t)i*32768;
  unsigned short* w2p = w1p + 16384;
  const float* w1 = l1_w + i*16384;
  const float* w2 = l2_w + i*16384;
  for (int k = threadIdx.x; k < 16384; k += 256) {
    int c = k >> 8, j = k & 255;
    int jt = j >> 4, hh = c >> 5, gg = (c >> 3) & 3, kp = c & 7;
    int l = gg*16 + (j & 15);
    w1p[jt*1024 + hh*512 + l*8 + kp] = f2bf(w1[k]);
    int j2 = k >> 6, c2 = k & 63;
    int ct = c2 >> 4, ks = j2 >> 5, g2 = (j2 >> 3) & 3, kp2 = j2 & 7;
    int l2 = g2*16 + (c2 & 15);
    w2p[(ct*8+ks)*512 + l2*8 + kp2] = f2bf(w2[k]);
  }
  const float* ck = conv_kw + i*4096;
  unsigned* cko = ckp2 + (size_t)i*2048;
  for (int idx = threadIdx.x; idx < 2048; idx += 256) {
    int p = idx >> 6, c = idx & 63;
    cko[idx] = (unsigned)f2h(ck[(2*p)*64 + c]) | ((unsigned)f2h(ck[(2*p+1)*64 + c]) << 16);
  }
  if (i == 0) {
    for (int idx = threadIdx.x; idx < 4096; idx += 256) {
      int fi = idx >> 9, l = (idx >> 3) & 63, kp = idx & 7;
      int ct = fi >> 1, ks = fi & 1, g = l >> 4, m = l & 15;
      w2f[idx] = f2h(sb_w2[(ks*32 + g*8 + kp)*64 + ct*16 + m]);
    }
  }
}

// ---------------------------------------------------------------------------
// Aggregation v3: single edge pass, 3 orientations fused per wave (ck is
// o-independent), 6 prefetched loads/edge, 3 independent fdot2 chains,
// f16 fk in LDS (18 KB -> ~6 blocks/CU).  Then conv-mix + LN -> bf16 xn.
// ---------------------------------------------------------------------------
__global__ __launch_bounds__(256) void k_aggr_f16(
    const unsigned* __restrict__ kb_u, const int* __restrict__ row_ptr,
    const int* __restrict__ e0s, const unsigned* __restrict__ ckp2,
    const float* __restrict__ g_fk_i, const float* __restrict__ conv_b,
    const float* __restrict__ ln_s, const float* __restrict__ ln_b,
    const float* __restrict__ h, unsigned short* __restrict__ xnb) {
  __shared__ unsigned short s_fkh[9216];
  __shared__ float s_x1[768];
  __shared__ float s_cb[64], s_ls[64], s_lb[64];
  __shared__ unsigned s_row[4][2][3][32];
  int tid = threadIdx.x;
  int wid = tid >> 6, lane = tid & 63;
  for (int i = tid; i < 9216; i += 256) s_fkh[i] = f2h(g_fk_i[i]);
  if (tid < 64) { s_cb[tid]=conv_b[tid]; s_ls[tid]=ln_s[tid]; s_lb[tid]=ln_b[tid]; }
  half2v ckreg[32];
#pragma unroll
  for (int p = 0; p < 32; ++p) ckreg[p] = u2h2(ckp2[p*64 + lane]);
  __syncthreads();
  int n = blockIdx.x;
  int lo = row_ptr[n], hi = row_ptr[n+1];
  int o0 = wid, o1 = wid + 4, o2 = wid + 8;
  float acc0 = 0.f, acc1 = 0.f, acc2 = 0.f;
  if (lo < hi) {
    unsigned k0 = 0, k1 = 0, k2 = 0;
    float h0, h1, h2;
    {
      int e0 = e0s[lo];
      if (lane < 32) {
        size_t kb = (size_t)lo*12;
        k0 = kb_u[(kb+o0)*32 + lane];
        k1 = kb_u[(kb+o1)*32 + lane];
        k2 = kb_u[(kb+o2)*32 + lane];
      }
      size_t hb = (size_t)e0*HC_;
      h0 = h[hb + o0*64 + lane];
      h1 = h[hb + o1*64 + lane];
      h2 = h[hb + o2*64 + lane];
    }
    int buf = 0;
    for (int s = lo; s < hi; ++s) {
      unsigned kc0 = k0, kc1 = k1, kc2 = k2;
      float hc0 = h0, hc1 = h1, hc2 = h2;
      if (s + 1 < hi) {
        int e0n = e0s[s+1];
        if (lane < 32) {
          size_t kb = (size_t)(s+1)*12;
          k0 = kb_u[(kb+o0)*32 + lane];
          k1 = kb_u[(kb+o1)*32 + lane];
          k2 = kb_u[(kb+o2)*32 + lane];
        }
        size_t hb = (size_t)e0n*HC_;
        h0 = h[hb + o0*64 + lane];
        h1 = h[hb + o1*64 + lane];
        h2 = h[hb + o2*64 + lane];
      }
      if (lane < 32) {
        s_row[wid][buf][0][lane] = kc0;
        s_row[wid][buf][1][lane] = kc1;
        s_row[wid][buf][2][lane] = kc2;
      }
      wave_sync();
      const uint4* ra = (const uint4*)s_row[wid][buf][0];
      const uint4* rb = (const uint4*)s_row[wid][buf][1];
      const uint4* rc = (const uint4*)s_row[wid][buf][2];
      float d0 = 0.f, d1 = 0.f, d2 = 0.f;
#pragma unroll
      for (int g = 0; g < 8; ++g) {
        uint4 va = ra[g], vb = rb[g], vc = rc[g];
        half2v c0 = ckreg[g*4+0], c1 = ckreg[g*4+1], c2 = ckreg[g*4+2], c3 = ckreg[g*4+3];
        d0 = FDOT2(u2h2(va.x), c0, d0); d0 = FDOT2(u2h2(va.y), c1, d0);
        d0 = FDOT2(u2h2(va.z), c2, d0); d0 = FDOT2(u2h2(va.w), c3, d0);
        d1 = FDOT2(u2h2(vb.x), c0, d1); d1 = FDOT2(u2h2(vb.y), c1, d1);
        d1 = FDOT2(u2h2(vb.z), c2, d1); d1 = FDOT2(u2h2(vb.w), c3, d1);
        d2 = FDOT2(u2h2(vc.x), c0, d2); d2 = FDOT2(u2h2(vc.y), c1, d2);
        d2 = FDOT2(u2h2(vc.z), c2, d2); d2 = FDOT2(u2h2(vc.w), c3, d2);
      }
      acc0 = fmaf(hc0, d0, acc0);
      acc1 = fmaf(hc1, d1, acc1);
      acc2 = fmaf(hc2, d2, acc2);
      buf ^= 1;
    }
  }
  s_x1[o0*64 + lane] = acc0;
  s_x1[o1*64 + lane] = acc1;
  s_x1[o2*64 + lane] = acc2;
  __syncthreads();
  for (int p = wid; p < 12; p += 4) {
    float a = 0.f;
#pragma unroll
    for (int o = 0; o < 12; ++o) a += s_x1[o*64+lane] * h2f(s_fkh[(p*12+o)*64 + lane]);
    a = a * (1.0f/12.0f) + s_cb[lane];
    float s1 = wave_sum64(a);
    float s2 = wave_sum64(a*a);
    float mu = s1 * (1.0f/64.0f);
    float var = s2 * (1.0f/64.0f) - mu*mu;
    float v = (a - mu) * rsqrtf(var + EPS_) * s_ls[lane] + s_lb[lane];
    xnb[(size_t)n*HC_ + p*64 + lane] = f2bf(v);
  }
}

// ---------------------------------------------------------------------------
// Node MLP via MFMA (bf16)
// ---------------------------------------------------------------------------
__global__ __launch_bounds__(512) void k_mlp_mfma(
    const unsigned short* __restrict__ xnb, float* __restrict__ h,
    const unsigned short* __restrict__ w1p, const unsigned short* __restrict__ w2p,
    const float* __restrict__ l1_b, const float* __restrict__ l2_b,
    const float* __restrict__ ro_w, const float* __restrict__ ro_b,
    float* __restrict__ racc) {
  __shared__ unsigned short s_w1p[16384];
  __shared__ unsigned short s_w2p[16384];
  __shared__ float s_b1[256];
  __shared__ float s_b2[64];
  __shared__ float s_ro[128];
  __shared__ unsigned short s_hm[8][16*272];
  int tid = threadIdx.x;
  {
    const uint4* a4 = (const uint4*)w1p;  uint4* d4 = (uint4*)s_w1p;
    const uint4* b4 = (const uint4*)w2p;  uint4* e4 = (uint4*)s_w2p;
    for (int k = tid; k < 2048; k += 512) { d4[k] = a4[k]; e4[k] = b4[k]; }
  }
  if (tid < 256) s_b1[tid] = l1_b[tid];
  if (tid < 64)  s_b2[tid] = l2_b[tid];
  if (tid < 128) s_ro[tid] = ro_w[tid];
  __syncthreads();
  int wid = tid >> 6, lane = tid & 63;
  int g = lane >> 4, m = lane & 15;
  float rb0 = ro_b[0], rb1 = ro_b[1];
  float b2v[4], rw0[4], rw1[4];
#pragma unroll
  for (int ct = 0; ct < 4; ++ct) {
    b2v[ct] = s_b2[ct*16 + m];
    rw0[ct] = s_ro[(ct*16+m)*2+0];
    rw1[ct] = s_ro[(ct*16+m)*2+1];
  }
  unsigned short* hm = s_hm[wid];
  int nwg = gridDim.x * 8;
  for (int rg = blockIdx.x*8 + wid; rg < 7500; rg += nwg) {
    int r0 = rg * 16;
    bf16x8 xb0 = *(const bf16x8*)(xnb + (size_t)(r0 + m)*64 + g*8);
    bf16x8 xb1 = *(const bf16x8*)(xnb + (size_t)(r0 + m)*64 + 32 + g*8);
    wave_sync();
#pragma unroll 4
    for (int jt = 0; jt < 16; ++jt) {
      bf16x8 a0 = *(const bf16x8*)(s_w1p + jt*1024 + lane*8);
      bf16x8 a1 = *(const bf16x8*)(s_w1p + jt*1024 + 512 + lane*8);
      f32x4 acc = {0.f, 0.f, 0.f, 0.f};
      acc = __builtin_amdgcn_mfma_f32_16x16x32_bf16(a0, xb0, acc, 0, 0, 0);
      acc = __builtin_amdgcn_mfma_f32_16x16x32_bf16(a1, xb1, acc, 0, 0, 0);
      float4 b1v = *(const float4*)&s_b1[jt*16 + g*4];
      float g0 = gelu_f(acc[0] + b1v.x);
      float g1 = gelu_f(acc[1] + b1v.y);
      float g2 = gelu_f(acc[2] + b1v.z);
      float g3 = gelu_f(acc[3] + b1v.w);
      unsigned wa = (unsigned)f2bf(g0) | ((unsigned)f2bf(g1) << 16);
      unsigned wb = (unsigned)f2bf(g2) | ((unsigned)f2bf(g3) << 16);
      *(uint2*)(hm + m*272 + jt*16 + g*4) = make_uint2(wa, wb);
    }
    wave_sync();
    f32x4 acc2[4];
#pragma unroll
    for (int ct = 0; ct < 4; ++ct) acc2[ct] = (f32x4){0.f, 0.f, 0.f, 0.f};
#pragma unroll
    for (int ks = 0; ks < 8; ++ks) {
      bf16x8 a2 = *(const bf16x8*)(hm + m*272 + ks*32 + g*8);
#pragma unroll
      for (int ct = 0; ct < 4; ++ct) {
        bf16x8 bf = *(const bf16x8*)(s_w2p + (ct*8+ks)*512 + lane*8);
        acc2[ct] = __builtin_amdgcn_mfma_f32_16x16x32_bf16(a2, bf, acc2[ct], 0, 0, 0);
      }
    }
    wave_sync();
#pragma unroll
    for (int reg = 0; reg < 4; ++reg) {
      int r = r0 + 4*g + reg;
      float v0 = 0.f, v1 = 0.f;
#pragma unroll
      for (int ct = 0; ct < 4; ++ct) {
        size_t idx = (size_t)r*64 + ct*16 + m;
        float hnew = acc2[ct][reg] + b2v[ct] + h[idx];
        h[idx] = hnew;
        v0 += hnew * rw0[ct];
        v1 += hnew * rw1[ct];
      }
#pragma unroll
      for (int off = 8; off > 0; off >>= 1) {
        v0 += __shfl_xor(v0, off, 16);
        v1 += __shfl_xor(v1, off, 16);
      }
      if (m == 0) {
        racc[r*2+0] += v0 + rb0;
        racc[r*2+1] += v1 + rb1;
      }
    }
  }
}

// ---------------------------------------------------------------------------
// Final segment-sum
// ---------------------------------------------------------------------------
__global__ __launch_bounds__(256) void k_final(
    const float* __restrict__ racc, const int* __restrict__ batch,
    const float* __restrict__ g_ori, float* __restrict__ out) {
  __shared__ float s_part[32];
  __shared__ float s_ori[36];
  int tid = threadIdx.x;
  if (tid < 32) s_part[tid] = 0.f;
  if (tid < 36) s_ori[tid] = g_ori[tid];
  __syncthreads();
  const float sc = 1.0f / 36.0f;
  for (int n = blockIdx.x*256 + tid; n < N_; n += gridDim.x*256) {
    int bt = batch[n];
    float ss = 0.f, v0 = 0.f, v1 = 0.f, v2 = 0.f;
#pragma unroll
    for (int o = 0; o < 12; ++o) {
      float r0 = racc[n*24 + o*2 + 0];
      float r1 = racc[n*24 + o*2 + 1];
      ss += r0;
      v0 += r1 * s_ori[o*3+0];
      v1 += r1 * s_ori[o*3+1];
      v2 += r1 * s_ori[o*3+2];
    }
    atomicAdd(&s_part[bt], ss*sc);
    atomicAdd(&s_part[8 + bt*3 + 0], v0*sc);
    atomicAdd(&s_part[8 + bt*3 + 1], v1*sc);
    atomicAdd(&s_part[8 + bt*3 + 2], v2*sc);
  }
  __syncthreads();
  if (tid < 32) atomicAdd(&out[tid], s_part[tid]);
}

extern "C" void kernel_launch(void* const* d_in, const int* in_sizes, int n_in,
                              void* d_out, int out_size, void* d_ws, size_t ws_size,
                              hipStream_t stream) {
  const float* pos    = (const float*)d_in[0];
  const float* x      = (const float*)d_in[1];
  const int*   ei     = (const int*)d_in[2];
  const int*   batch  = (const int*)d_in[3];
  const float* sb_w1  = (const float*)d_in[4];
  const float* sb_b1  = (const float*)d_in[5];
  const float* sb_w2  = (const float*)d_in[6];
  const float* sb_b2  = (const float*)d_in[7];
  const float* fb_w1  = (const float*)d_in[8];
  const float* fb_b1  = (const float*)d_in[9];
  const float* fb_w2  = (const float*)d_in[10];
  const float* fb_b2  = (const float*)d_in[11];
  const float* emb_w  = (const float*)d_in[12];
  const float* conv_kw= (const float*)d_in[13];
  const float* fib_kw = (const float*)d_in[14];
  const float* conv_b = (const float*)d_in[15];
  const float* ln_s   = (const float*)d_in[16];
  const float* ln_b   = (const float*)d_in[17];
  const float* l1_w   = (const float*)d_in[18];
  const float* l1_b   = (const float*)d_in[19];
  const float* l2_w   = (const float*)d_in[20];
  const float* l2_b   = (const float*)d_in[21];
  const float* ro_w   = (const float*)d_in[22];
  const float* ro_b   = (const float*)d_in[23];

  float* ws_f   = (float*)d_ws;
  float* g_ori  = ws_f + OFF_ORI;
  float* g_fk   = ws_f + OFF_FK;
  float* g_h    = ws_f + OFF_H;
  unsigned short* g_xnb = (unsigned short*)(ws_f + OFF_XNB);
  float* g_racc = ws_f + OFF_RACC;
  int*   row_ptr= (int*)(ws_f + OFF_RP);
  int*   cursor = (int*)(ws_f + OFF_CUR);
  int*   e0s    = (int*)(ws_f + OFF_E0S);
  float4* rel4  = (float4*)(ws_f + OFF_REL);
  unsigned short* g_wp  = (unsigned short*)(ws_f + OFF_WP);
  unsigned*       g_ckp = (unsigned*)(ws_f + OFF_CKP);
  unsigned short* g_w2f = (unsigned short*)(ws_f + OFF_W2F);
  unsigned*       kb_u  = (unsigned*)(ws_f + OFF_KB);
  float* out_f  = (float*)d_out;

  (void)hipMemsetAsync(g_racc, 0, 240000*sizeof(float), stream);
  k_setup<<<3, 256, 0, stream>>>(fb_w1, fb_b1, fb_w2, fb_b2, fib_kw, g_ori, g_fk);
  k_embed<<<512, 256, 0, stream>>>(x, emb_w, g_h);

  (void)hipMemsetAsync(cursor, 0, (N_+1)*sizeof(int), stream);
  k_count<<<(E_+255)/256, 256, 0, stream>>>(ei, cursor);
  k_scan<<<1, 256, 0, stream>>>(cursor, row_ptr);
  k_scatter<<<(E_+255)/256, 256, 0, stream>>>(pos, ei, cursor, e0s, rel4);
  k_sortbins<<<(N_+255)/256, 256, 0, stream>>>(row_ptr, e0s, rel4);
  k_pack<<<3, 256, 0, stream>>>(l1_w, l2_w, conv_kw, sb_w2, g_wp, g_ckp, g_w2f);
  k_basis_v2<<<3750, 256, 0, stream>>>(rel4, sb_w1, sb_b1, g_w2f, sb_b2, g_ori, kb_u);
  for (int i = 0; i < 3; ++i) {
    k_aggr_f16<<<N_, 256, 0, stream>>>(kb_u, row_ptr, e0s, g_ckp + (size_t)i*2048,
                                       g_fk + i*9216, conv_b + i*64,
                                       ln_s + i*64, ln_b + i*64, g_h, g_xnb);
    k_mlp_mfma<<<256, 512, 0, stream>>>(g_xnb, g_h,
                                        g_wp + (size_t)i*32768, g_wp + (size_t)i*32768 + 16384,
                                        l1_b + i*256, l2_b + i*64,
                                        ro_w + i*128, ro_b + i*2, g_racc);
  }
  (void)hipMemsetAsync(out_f, 0, 32*sizeof(float), stream);
  k_final<<<128, 256, 0, stream>>>(g_racc, batch, g_ori, out_f);
}

// Round 14
// 716.162 us; speedup vs baseline: 2.4712x; 1.0161x over previous
//
#include <hip/hip_runtime.h>
#include <math.h>

namespace {
constexpr int N_   = 10000;
constexpr int E_   = 80000;
constexpr int ORI_ = 12;
constexpr int HC_  = 768;   // ORI*C
constexpr float EPS_ = 1e-6f;
constexpr int NPB_ = 4;     // nodes per aggregation block

// workspace layout (float units) — total ~172 MB (proven ws >= 187 MB)
constexpr size_t OFF_ORI  = 0;                        // 64
constexpr size_t OFF_FK   = 64;                       // 27648 (fp32 fk)
constexpr size_t OFF_FKH  = OFF_FK + 27648;           // 13824 (f16 fk, 3*9216 u16)
constexpr size_t OFF_H    = OFF_FKH + 13824;          // 7,680,000 (fp32 h)
constexpr size_t OFF_XNB  = OFF_H + 7680000;          // 3,840,000 (bf16 xn)
constexpr size_t OFF_RACC = OFF_XNB + 3840000;        // 240,000
constexpr size_t OFF_RP   = OFF_RACC + 240000;        // 10001 ints
constexpr size_t OFF_CUR  = OFF_RP + 10001;           // 10001 ints
constexpr size_t OFF_E0S  = OFF_CUR + 10001;          // 80000 ints
constexpr size_t OFF_REL  = ((OFF_E0S + 80000 + 3) / 4) * 4;   // 80000 float4
constexpr size_t OFF_WP   = ((OFF_REL + 320000 + 3) / 4) * 4;  // 3*32768 u16 (MLP)
constexpr size_t OFF_CKP  = OFF_WP + 49152;           // 3*2048 u32 f16-pairs
constexpr size_t OFF_W2F  = OFF_CKP + 6144;           // 4096 u16 basis-w2 f16 frags
constexpr size_t OFF_KB   = OFF_W2F + 2048;           // f16 kb: 960000 rows * 32 u32
constexpr size_t KB_F     = (size_t)E_ * ORI_ * 64 / 2;        // 30,720,000 f
}

typedef short bf16x8 __attribute__((ext_vector_type(8)));
typedef _Float16 f16x8 __attribute__((ext_vector_type(8)));
typedef float f32x4  __attribute__((ext_vector_type(4)));
typedef _Float16 half2v __attribute__((ext_vector_type(2)));

#if __has_builtin(__builtin_amdgcn_fdot2)
#define FDOT2(a,b,c) __builtin_amdgcn_fdot2((a),(b),(c),false)
#else
__device__ __forceinline__ float FDOT2(half2v a, half2v b, float c) {
  return c + (float)a.x*(float)b.x + (float)a.y*(float)b.y;
}
#endif

__device__ __forceinline__ float gelu_f(float x) {
  float x2 = x * x;
  float u  = x * fmaf(x2, 0.10294324f, 2.30220826f);
  float t  = __builtin_amdgcn_exp2f(u);
  float r  = __builtin_amdgcn_rcpf(t + 1.0f);
  return fmaf(-x, r, x);
}

__device__ __forceinline__ void wave_sync() {
  asm volatile("s_waitcnt lgkmcnt(0)" ::: "memory");
  __builtin_amdgcn_wave_barrier();
}

__device__ __forceinline__ float wave_sum64(float v) {
#pragma unroll
  for (int off = 32; off > 0; off >>= 1) v += __shfl_xor(v, off, 64);
  return v;
}

__device__ __forceinline__ unsigned short f2bf(float x) {
  unsigned u = __float_as_uint(x);
  unsigned r = (u + 0x7fffu + ((u >> 16) & 1u)) >> 16;  // RNE
  return (unsigned short)r;
}

__device__ __forceinline__ unsigned short f2h(float x) {
  _Float16 h = (_Float16)x;
  unsigned short u;
  __builtin_memcpy(&u, &h, 2);
  return u;
}

__device__ __forceinline__ float h2f(unsigned short u) {
  _Float16 h;
  __builtin_memcpy(&h, &u, 2);
  return (float)h;
}

__device__ __forceinline__ _Float16 f2hh(float x) { return (_Float16)x; }

__device__ __forceinline__ half2v u2h2(unsigned u) {
  half2v h;
  __builtin_memcpy(&h, &u, 4);
  return h;
}

// ---------------------------------------------------------------------------
// Setup: grid=3 (one block per layer), all weights LDS-staged.
// Emits fp32 fk (for nothing now, kept) and f16 fk for aggregation.
// ---------------------------------------------------------------------------
__global__ __launch_bounds__(256) void k_setup(
    const float* __restrict__ fb_w1, const float* __restrict__ fb_b1,
    const float* __restrict__ fb_w2, const float* __restrict__ fb_b2,
    const float* __restrict__ fib_kw,
    float* __restrict__ g_ori, float* __restrict__ g_fk,
    unsigned short* __restrict__ g_fkh) {
  __shared__ float s_ori[36];
  __shared__ float s_w1[192];
  __shared__ float s_b1[64], s_b2[64];
  __shared__ float s_w2[4096];
  __shared__ float s_fib[4096];
  __shared__ float s_h1[144*64];
  __shared__ float s_kb[144*64];
  int tid = threadIdx.x;
  int i = blockIdx.x;
  if (tid < 12) {
    const double PI = 3.14159265358979323846;
    double th = fmod(PI * (double)tid * (1.0 + sqrt(5.0)), 2.0 * PI);
    double ph = acos(1.0 - 2.0 * ((double)tid + 0.5) / 12.0);
    float sx = (float)(sin(ph) * cos(th));
    float sy = (float)(sin(ph) * sin(th));
    float sz = (float)cos(ph);
    s_ori[tid*3+0]=sx; s_ori[tid*3+1]=sy; s_ori[tid*3+2]=sz;
    if (i == 0) { g_ori[tid*3+0]=sx; g_ori[tid*3+1]=sy; g_ori[tid*3+2]=sz; }
  }
  for (int k = tid; k < 4096; k += 256) { s_w2[k] = fb_w2[k]; s_fib[k] = fib_kw[i*4096 + k]; }
  if (tid < 192) s_w1[tid] = fb_w1[tid];
  if (tid < 64) { s_b1[tid] = fb_b1[tid]; s_b2[tid] = fb_b2[tid]; }
  __syncthreads();
  int wid = tid >> 6, lane = tid & 63;
  for (int r = wid; r < 144; r += 4) {
    int p = r / 12, o = r % 12;
    float s = s_ori[p*3+0]*s_ori[o*3+0] + s_ori[p*3+1]*s_ori[o*3+1] + s_ori[p*3+2]*s_ori[o*3+2];
    float f1 = s, f2 = s*s, f3 = s*s*s;
    float a1 = s_b1[lane] + f1*s_w1[lane] + f2*s_w1[64+lane] + f3*s_w1[128+lane];
    s_h1[r*64+lane] = gelu_f(a1);
  }
  __syncthreads();
  for (int r = wid; r < 144; r += 4) {
    float a2 = s_b2[lane];
    for (int j = 0; j < 64; ++j) a2 += s_h1[r*64+j] * s_w2[j*64+lane];
    s_kb[r*64+lane] = gelu_f(a2);
  }
  __syncthreads();
  for (int r = wid; r < 144; r += 4) {
    float acc = 0.f;
    for (int j = 0; j < 64; ++j) acc += s_kb[r*64+j] * s_fib[j*64+lane];
    g_fk[i*9216 + r*64 + lane] = acc;
    g_fkh[i*9216 + r*64 + lane] = f2h(acc);
  }
}

// ---------------------------------------------------------------------------
// Embed
// ---------------------------------------------------------------------------
__global__ __launch_bounds__(256) void k_embed(
    const float* __restrict__ x, const float* __restrict__ emb_w,
    float* __restrict__ h) {
  __shared__ float s_w[16*64];
  int tid = threadIdx.x;
  for (int i = tid; i < 16*64; i += 256) s_w[i] = emb_w[i];
  __syncthreads();
  int wid = tid >> 6, lane = tid & 63;
  int nw = gridDim.x * 4;
  for (int n = blockIdx.x*4 + wid; n < N_; n += nw) {
    float acc = 0.f;
#pragma unroll
    for (int k = 0; k < 16; ++k) acc += x[n*16+k] * s_w[k*64+lane];
#pragma unroll
    for (int o = 0; o < ORI_; ++o) h[n*HC_ + o*64 + lane] = acc;
  }
}

// ---------------------------------------------------------------------------
// CSR build
// ---------------------------------------------------------------------------
__global__ __launch_bounds__(256) void k_count(const int* __restrict__ ei, int* __restrict__ cnt) {
  int e = blockIdx.x*256 + threadIdx.x;
  if (e < E_) atomicAdd(&cnt[ei[E_ + e]], 1);
}

__global__ __launch_bounds__(256) void k_scan(int* __restrict__ cnt, int* __restrict__ row_ptr) {
  __shared__ int s_sum[256];
  int tid = threadIdx.x;
  int start = tid * 40, end = min(start + 40, N_);
  int s = 0;
  for (int i = start; i < end; ++i) s += cnt[i];
  s_sum[tid] = s;
  __syncthreads();
  if (tid == 0) {
    int run = 0;
    for (int i = 0; i < 256; ++i) { int t = s_sum[i]; s_sum[i] = run; run += t; }
  }
  __syncthreads();
  int run = s_sum[tid];
  for (int i = start; i < end; ++i) { int c = cnt[i]; row_ptr[i] = run; cnt[i] = run; run += c; }
  if (tid == 0) row_ptr[N_] = E_;
}

__global__ __launch_bounds__(256) void k_scatter(
    const float* __restrict__ pos, const int* __restrict__ ei,
    int* __restrict__ cursor, int* __restrict__ e0s, float4* __restrict__ rel4) {
  int e = blockIdx.x*256 + threadIdx.x;
  if (e >= E_) return;
  int a = ei[e], b = ei[E_ + e];
  int slot = atomicAdd(&cursor[b], 1);
  float rx = pos[a*3+0]-pos[b*3+0];
  float ry = pos[a*3+1]-pos[b*3+1];
  float rz = pos[a*3+2]-pos[b*3+2];
  e0s[slot] = a;
  rel4[slot] = make_float4(rx, ry, rz, __int_as_float(e));
}

__global__ __launch_bounds__(256) void k_sortbins(
    const int* __restrict__ row_ptr, int* __restrict__ e0s, float4* __restrict__ rel4) {
  int n = blockIdx.x*256 + threadIdx.x;
  if (n >= N_) return;
  int lo = row_ptr[n], hi = row_ptr[n+1];
  for (int i = lo + 1; i < hi; ++i) {
    float4 key = rel4[i]; int kk = __float_as_int(key.w); int ke = e0s[i];
    int j = i - 1;
    while (j >= lo && __float_as_int(rel4[j].w) > kk) {
      rel4[j+1] = rel4[j]; e0s[j+1] = e0s[j]; --j;
    }
    rel4[j+1] = key; e0s[j+1] = ke;
  }
}

// ---------------------------------------------------------------------------
// Basis v2: stage1 on VALU (K=14), stage2 via f16 MFMA.
// ---------------------------------------------------------------------------
__global__ __launch_bounds__(256) void k_basis_v2(
    const float4* __restrict__ rel4,
    const float* __restrict__ sb_w1, const float* __restrict__ sb_b1,
    const unsigned short* __restrict__ w2f, const float* __restrict__ sb_b2,
    const float* __restrict__ g_ori, unsigned* __restrict__ kb_u) {
  __shared__ float s_w1[14*64];
  __shared__ float s_b1[64];
  __shared__ float s_b2[64];
  __shared__ float s_ori[36];
  __shared__ unsigned short s_st[4][1024];
  int tid = threadIdx.x;
  int wid = tid >> 6, lane = tid & 63;
  int g = lane >> 4, m = lane & 15;
  for (int i = tid; i < 14*64; i += 256) s_w1[i] = sb_w1[i];
  if (tid < 64) { s_b1[tid] = sb_b1[tid]; s_b2[tid] = sb_b2[tid]; }
  if (tid < 36) s_ori[tid] = g_ori[tid];
  f16x8 wf[8];
#pragma unroll
  for (int fi = 0; fi < 8; ++fi) wf[fi] = *(const f16x8*)(w2f + fi*512 + lane*8);
  float b2v[4];
  __syncthreads();
#pragma unroll
  for (int ct = 0; ct < 4; ++ct) b2v[ct] = s_b2[ct*16 + m];
  unsigned short* st = s_st[wid];
  unsigned short* kb16 = (unsigned short*)kb_u;
  for (int t = blockIdx.x*4 + wid; t < 60000; t += 15000) {
    int r0 = t * 16;
    int r = r0 + m;
    int s = r / 12, o = r - s*12;
    float4 rv = rel4[s];
    float rx = rv.x, ry = rv.y, rz = rv.z;
    float ox = s_ori[o*3+0], oy = s_ori[o*3+1], oz = s_ori[o*3+2];
    float i1 = rx*ox + ry*oy + rz*oz;
    float px = rx - i1*ox, py = ry - i1*oy, pz = rz - i1*oz;
    float i2 = sqrtf(px*px + py*py + pz*pz);
    float f[14];
    f[0]=i1; f[1]=i2; f[2]=i1*i1; f[3]=i1*i2; f[4]=i2*i1; f[5]=i2*i2;
    f[6]=f[2]*i1; f[7]=f[2]*i2; f[8]=f[3]*i1; f[9]=f[3]*i2;
    f[10]=f[4]*i1; f[11]=f[4]*i2; f[12]=f[5]*i1; f[13]=f[5]*i2;
    f16x8 a0, a1;
#pragma unroll
    for (int hh = 0; hh < 2; ++hh) {
      int bc = hh*32 + g*8;
      float4 ac0 = *(const float4*)&s_b1[bc];
      float4 ac1 = *(const float4*)&s_b1[bc+4];
#pragma unroll
      for (int p = 0; p < 14; ++p) {
        float fp = f[p];
        float4 w0 = *(const float4*)&s_w1[p*64 + bc];
        float4 w1v = *(const float4*)&s_w1[p*64 + bc + 4];
        ac0.x += fp*w0.x; ac0.y += fp*w0.y; ac0.z += fp*w0.z; ac0.w += fp*w0.w;
        ac1.x += fp*w1v.x; ac1.y += fp*w1v.y; ac1.z += fp*w1v.z; ac1.w += fp*w1v.w;
      }
      f16x8& dst = hh ? a1 : a0;
      dst[0] = f2hh(gelu_f(ac0.x)); dst[1] = f2hh(gelu_f(ac0.y));
      dst[2] = f2hh(gelu_f(ac0.z)); dst[3] = f2hh(gelu_f(ac0.w));
      dst[4] = f2hh(gelu_f(ac1.x)); dst[5] = f2hh(gelu_f(ac1.y));
      dst[6] = f2hh(gelu_f(ac1.z)); dst[7] = f2hh(gelu_f(ac1.w));
    }
    f32x4 acc[4];
#pragma unroll
    for (int ct = 0; ct < 4; ++ct) {
      acc[ct] = (f32x4){0.f, 0.f, 0.f, 0.f};
      acc[ct] = __builtin_amdgcn_mfma_f32_16x16x32_f16(a0, wf[ct*2+0], acc[ct], 0, 0, 0);
      acc[ct] = __builtin_amdgcn_mfma_f32_16x16x32_f16(a1, wf[ct*2+1], acc[ct], 0, 0, 0);
    }
#pragma unroll
    for (int ct = 0; ct < 4; ++ct) {
#pragma unroll
      for (int reg = 0; reg < 4; ++reg) {
        int row = 4*g + reg;
        int col = (ct*16 + m) ^ (g << 4);
        st[row*64 + col] = f2h(gelu_f(acc[ct][reg] + b2v[ct]));
      }
    }
    wave_sync();
#pragma unroll
    for (int p2 = 0; p2 < 2; ++p2) {
      int row = p2*8 + (lane >> 3);
      int cb  = (lane & 7) * 8;
      int sc  = cb ^ (((row >> 2) & 3) << 4);
      uint4 v = *(const uint4*)(st + row*64 + sc);
      *(uint4*)(kb16 + (size_t)r0*64 + p2*512 + lane*8) = v;
    }
    wave_sync();
  }
}

// ---------------------------------------------------------------------------
// Pack weights (once)
// ---------------------------------------------------------------------------
__global__ __launch_bounds__(256) void k_pack(
    const float* __restrict__ l1_w, const float* __restrict__ l2_w,
    const float* __restrict__ conv_kw, const float* __restrict__ sb_w2,
    unsigned short* __restrict__ wp, unsigned* __restrict__ ckp2,
    unsigned short* __restrict__ w2f) {
  int i = blockIdx.x;
  unsigned short* w1p = wp + (size_t)i*32768;
  unsigned short* w2p = w1p + 16384;
  const float* w1 = l1_w + i*16384;
  const float* w2 = l2_w + i*16384;
  for (int k = threadIdx.x; k < 16384; k += 256) {
    int c = k >> 8, j = k & 255;
    int jt = j >> 4, hh = c >> 5, gg = (c >> 3) & 3, kp = c & 7;
    int l = gg*16 + (j & 15);
    w1p[jt*1024 + hh*512 + l*8 + kp] = f2bf(w1[k]);
    int j2 = k >> 6, c2 = k & 63;
    int ct = c2 >> 4, ks = j2 >> 5, g2 = (j2 >> 3) & 3, kp2 = j2 & 7;
    int l2 = g2*16 + (c2 & 15);
    w2p[(ct*8+ks)*512 + l2*8 + kp2] = f2bf(w2[k]);
  }
  const float* ck = conv_kw + i*4096;
  unsigned* cko = ckp2 + (size_t)i*2048;
  for (int idx = threadIdx.x; idx < 2048; idx += 256) {
    int p = idx >> 6, c = idx & 63;
    cko[idx] = (unsigned)f2h(ck[(2*p)*64 + c]) | ((unsigned)f2h(ck[(2*p+1)*64 + c]) << 16);
  }
  if (i == 0) {
    for (int idx = threadIdx.x; idx < 4096; idx += 256) {
      int fi = idx >> 9, l = (idx >> 3) & 63, kp = idx & 7;
      int ct = fi >> 1, ks = fi & 1, g = l >> 4, m = l & 15;
      w2f[idx] = f2h(sb_w2[(ks*32 + g*8 + kp)*64 + ct*16 + m]);
    }
  }
}

// ---------------------------------------------------------------------------
// Aggregation v4: 4 nodes/block, fk staged once (f16, plain copy), 3-o-fused
// edge loop with prefetch + 3 fdot2 chains, then conv-mix + LN per node.
// ---------------------------------------------------------------------------
__global__ __launch_bounds__(256) void k_aggr_f16(
    const unsigned* __restrict__ kb_u, const int* __restrict__ row_ptr,
    const int* __restrict__ e0s, const unsigned* __restrict__ ckp2,
    const unsigned short* __restrict__ g_fkh_i, const float* __restrict__ conv_b,
    const float* __restrict__ ln_s, const float* __restrict__ ln_b,
    const float* __restrict__ h, unsigned short* __restrict__ xnb) {
  __shared__ unsigned short s_fkh[9216];
  __shared__ float s_x1[NPB_*768];
  __shared__ float s_cb[64], s_ls[64], s_lb[64];
  __shared__ unsigned s_row[4][2][3][32];
  int tid = threadIdx.x;
  int wid = tid >> 6, lane = tid & 63;
  {
    const unsigned* src = (const unsigned*)g_fkh_i;
    unsigned* dst = (unsigned*)s_fkh;
    for (int i = tid; i < 4608; i += 256) dst[i] = src[i];
  }
  if (tid < 64) { s_cb[tid]=conv_b[tid]; s_ls[tid]=ln_s[tid]; s_lb[tid]=ln_b[tid]; }
  half2v ckreg[32];
#pragma unroll
  for (int p = 0; p < 32; ++p) ckreg[p] = u2h2(ckp2[p*64 + lane]);
  __syncthreads();
  int o0 = wid, o1 = wid + 4, o2 = wid + 8;
#pragma unroll 1
  for (int ln = 0; ln < NPB_; ++ln) {
    int n = blockIdx.x*NPB_ + ln;
    int lo = row_ptr[n], hi = row_ptr[n+1];
    float acc0 = 0.f, acc1 = 0.f, acc2 = 0.f;
    if (lo < hi) {
      unsigned k0 = 0, k1 = 0, k2 = 0;
      float h0, h1, h2;
      {
        int e0 = e0s[lo];
        if (lane < 32) {
          size_t kb = (size_t)lo*12;
          k0 = kb_u[(kb+o0)*32 + lane];
          k1 = kb_u[(kb+o1)*32 + lane];
          k2 = kb_u[(kb+o2)*32 + lane];
        }
        size_t hb = (size_t)e0*HC_;
        h0 = h[hb + o0*64 + lane];
        h1 = h[hb + o1*64 + lane];
        h2 = h[hb + o2*64 + lane];
      }
      int buf = 0;
      for (int s = lo; s < hi; ++s) {
        unsigned kc0 = k0, kc1 = k1, kc2 = k2;
        float hc0 = h0, hc1 = h1, hc2 = h2;
        if (s + 1 < hi) {
          int e0n = e0s[s+1];
          if (lane < 32) {
            size_t kb = (size_t)(s+1)*12;
            k0 = kb_u[(kb+o0)*32 + lane];
            k1 = kb_u[(kb+o1)*32 + lane];
            k2 = kb_u[(kb+o2)*32 + lane];
          }
          size_t hb = (size_t)e0n*HC_;
          h0 = h[hb + o0*64 + lane];
          h1 = h[hb + o1*64 + lane];
          h2 = h[hb + o2*64 + lane];
        }
        if (lane < 32) {
          s_row[wid][buf][0][lane] = kc0;
          s_row[wid][buf][1][lane] = kc1;
          s_row[wid][buf][2][lane] = kc2;
        }
        wave_sync();
        const uint4* ra = (const uint4*)s_row[wid][buf][0];
        const uint4* rb = (const uint4*)s_row[wid][buf][1];
        const uint4* rc = (const uint4*)s_row[wid][buf][2];
        float d0 = 0.f, d1 = 0.f, d2 = 0.f;
#pragma unroll
        for (int g = 0; g < 8; ++g) {
          uint4 va = ra[g], vb = rb[g], vc = rc[g];
          half2v c0 = ckreg[g*4+0], c1 = ckreg[g*4+1], c2 = ckreg[g*4+2], c3 = ckreg[g*4+3];
          d0 = FDOT2(u2h2(va.x), c0, d0); d0 = FDOT2(u2h2(va.y), c1, d0);
          d0 = FDOT2(u2h2(va.z), c2, d0); d0 = FDOT2(u2h2(va.w), c3, d0);
          d1 = FDOT2(u2h2(vb.x), c0, d1); d1 = FDOT2(u2h2(vb.y), c1, d1);
          d1 = FDOT2(u2h2(vb.z), c2, d1); d1 = FDOT2(u2h2(vb.w), c3, d1);
          d2 = FDOT2(u2h2(vc.x), c0, d2); d2 = FDOT2(u2h2(vc.y), c1, d2);
          d2 = FDOT2(u2h2(vc.z), c2, d2); d2 = FDOT2(u2h2(vc.w), c3, d2);
        }
        acc0 = fmaf(hc0, d0, acc0);
        acc1 = fmaf(hc1, d1, acc1);
        acc2 = fmaf(hc2, d2, acc2);
        buf ^= 1;
      }
    }
    s_x1[ln*768 + o0*64 + lane] = acc0;
    s_x1[ln*768 + o1*64 + lane] = acc1;
    s_x1[ln*768 + o2*64 + lane] = acc2;
  }
  __syncthreads();
  for (int idx = wid; idx < NPB_*12; idx += 4) {
    int ln = idx & (NPB_-1);
    int p  = idx >> 2;
    float a = 0.f;
#pragma unroll
    for (int o = 0; o < 12; ++o) a += s_x1[ln*768 + o*64 + lane] * h2f(s_fkh[(p*12+o)*64 + lane]);
    a = a * (1.0f/12.0f) + s_cb[lane];
    float s1 = wave_sum64(a);
    float s2 = wave_sum64(a*a);
    float mu = s1 * (1.0f/64.0f);
    float var = s2 * (1.0f/64.0f) - mu*mu;
    float v = (a - mu) * rsqrtf(var + EPS_) * s_ls[lane] + s_lb[lane];
    xnb[(size_t)(blockIdx.x*NPB_ + ln)*HC_ + p*64 + lane] = f2bf(v);
  }
}

// ---------------------------------------------------------------------------
// Node MLP via MFMA (bf16)
// ---------------------------------------------------------------------------
__global__ __launch_bounds__(512) void k_mlp_mfma(
    const unsigned short* __restrict__ xnb, float* __restrict__ h,
    const unsigned short* __restrict__ w1p, const unsigned short* __restrict__ w2p,
    const float* __restrict__ l1_b, const float* __restrict__ l2_b,
    const float* __restrict__ ro_w, const float* __restrict__ ro_b,
    float* __restrict__ racc) {
  __shared__ unsigned short s_w1p[16384];
  __shared__ unsigned short s_w2p[16384];
  __shared__ float s_b1[256];
  __shared__ float s_b2[64];
  __shared__ float s_ro[128];
  __shared__ unsigned short s_hm[8][16*272];
  int tid = threadIdx.x;
  {
    const uint4* a4 = (const uint4*)w1p;  uint4* d4 = (uint4*)s_w1p;
    const uint4* b4 = (const uint4*)w2p;  uint4* e4 = (uint4*)s_w2p;
    for (int k = tid; k < 2048; k += 512) { d4[k] = a4[k]; e4[k] = b4[k]; }
  }
  if (tid < 256) s_b1[tid] = l1_b[tid];
  if (tid < 64)  s_b2[tid] = l2_b[tid];
  if (tid < 128) s_ro[tid] = ro_w[tid];
  __syncthreads();
  int wid = tid >> 6, lane = tid & 63;
  int g = lane >> 4, m = lane & 15;
  float rb0 = ro_b[0], rb1 = ro_b[1];
  float b2v[4], rw0[4], rw1[4];
#pragma unroll
  for (int ct = 0; ct < 4; ++ct) {
    b2v[ct] = s_b2[ct*16 + m];
    rw0[ct] = s_ro[(ct*16+m)*2+0];
    rw1[ct] = s_ro[(ct*16+m)*2+1];
  }
  unsigned short* hm = s_hm[wid];
  int nwg = gridDim.x * 8;
  for (int rg = blockIdx.x*8 + wid; rg < 7500; rg += nwg) {
    int r0 = rg * 16;
    bf16x8 xb0 = *(const bf16x8*)(xnb + (size_t)(r0 + m)*64 + g*8);
    bf16x8 xb1 = *(const bf16x8*)(xnb + (size_t)(r0 + m)*64 + 32 + g*8);
    wave_sync();
#pragma unroll 4
    for (int jt = 0; jt < 16; ++jt) {
      bf16x8 a0 = *(const bf16x8*)(s_w1p + jt*1024 + lane*8);
      bf16x8 a1 = *(const bf16x8*)(s_w1p + jt*1024 + 512 + lane*8);
      f32x4 acc = {0.f, 0.f, 0.f, 0.f};
      acc = __builtin_amdgcn_mfma_f32_16x16x32_bf16(a0, xb0, acc, 0, 0, 0);
      acc = __builtin_amdgcn_mfma_f32_16x16x32_bf16(a1, xb1, acc, 0, 0, 0);
      float4 b1v = *(const float4*)&s_b1[jt*16 + g*4];
      float g0 = gelu_f(acc[0] + b1v.x);
      float g1 = gelu_f(acc[1] + b1v.y);
      float g2 = gelu_f(acc[2] + b1v.z);
      float g3 = gelu_f(acc[3] + b1v.w);
      unsigned wa = (unsigned)f2bf(g0) | ((unsigned)f2bf(g1) << 16);
      unsigned wb = (unsigned)f2bf(g2) | ((unsigned)f2bf(g3) << 16);
      *(uint2*)(hm + m*272 + jt*16 + g*4) = make_uint2(wa, wb);
    }
    wave_sync();
    f32x4 acc2[4];
#pragma unroll
    for (int ct = 0; ct < 4; ++ct) acc2[ct] = (f32x4){0.f, 0.f, 0.f, 0.f};
#pragma unroll
    for (int ks = 0; ks < 8; ++ks) {
      bf16x8 a2 = *(const bf16x8*)(hm + m*272 + ks*32 + g*8);
#pragma unroll
      for (int ct = 0; ct < 4; ++ct) {
        bf16x8 bf = *(const bf16x8*)(s_w2p + (ct*8+ks)*512 + lane*8);
        acc2[ct] = __builtin_amdgcn_mfma_f32_16x16x32_bf16(a2, bf, acc2[ct], 0, 0, 0);
      }
    }
    wave_sync();
#pragma unroll
    for (int reg = 0; reg < 4; ++reg) {
      int r = r0 + 4*g + reg;
      float v0 = 0.f, v1 = 0.f;
#pragma unroll
      for (int ct = 0; ct < 4; ++ct) {
        size_t idx = (size_t)r*64 + ct*16 + m;
        float hnew = acc2[ct][reg] + b2v[ct] + h[idx];
        h[idx] = hnew;
        v0 += hnew * rw0[ct];
        v1 += hnew * rw1[ct];
      }
#pragma unroll
      for (int off = 8; off > 0; off >>= 1) {
        v0 += __shfl_xor(v0, off, 16);
        v1 += __shfl_xor(v1, off, 16);
      }
      if (m == 0) {
        racc[r*2+0] += v0 + rb0;
        racc[r*2+1] += v1 + rb1;
      }
    }
  }
}

// ---------------------------------------------------------------------------
// Final segment-sum
// ---------------------------------------------------------------------------
__global__ __launch_bounds__(256) void k_final(
    const float* __restrict__ racc, const int* __restrict__ batch,
    const float* __restrict__ g_ori, float* __restrict__ out) {
  __shared__ float s_part[32];
  __shared__ float s_ori[36];
  int tid = threadIdx.x;
  if (tid < 32) s_part[tid] = 0.f;
  if (tid < 36) s_ori[tid] = g_ori[tid];
  __syncthreads();
  const float sc = 1.0f / 36.0f;
  for (int n = blockIdx.x*256 + tid; n < N_; n += gridDim.x*256) {
    int bt = batch[n];
    float ss = 0.f, v0 = 0.f, v1 = 0.f, v2 = 0.f;
#pragma unroll
    for (int o = 0; o < 12; ++o) {
      float r0 = racc[n*24 + o*2 + 0];
      float r1 = racc[n*24 + o*2 + 1];
      ss += r0;
      v0 += r1 * s_ori[o*3+0];
      v1 += r1 * s_ori[o*3+1];
      v2 += r1 * s_ori[o*3+2];
    }
    atomicAdd(&s_part[bt], ss*sc);
    atomicAdd(&s_part[8 + bt*3 + 0], v0*sc);
    atomicAdd(&s_part[8 + bt*3 + 1], v1*sc);
    atomicAdd(&s_part[8 + bt*3 + 2], v2*sc);
  }
  __syncthreads();
  if (tid < 32) atomicAdd(&out[tid], s_part[tid]);
}

extern "C" void kernel_launch(void* const* d_in, const int* in_sizes, int n_in,
                              void* d_out, int out_size, void* d_ws, size_t ws_size,
                              hipStream_t stream) {
  const float* pos    = (const float*)d_in[0];
  const float* x      = (const float*)d_in[1];
  const int*   ei     = (const int*)d_in[2];
  const int*   batch  = (const int*)d_in[3];
  const float* sb_w1  = (const float*)d_in[4];
  const float* sb_b1  = (const float*)d_in[5];
  const float* sb_w2  = (const float*)d_in[6];
  const float* sb_b2  = (const float*)d_in[7];
  const float* fb_w1  = (const float*)d_in[8];
  const float* fb_b1  = (const float*)d_in[9];
  const float* fb_w2  = (const float*)d_in[10];
  const float* fb_b2  = (const float*)d_in[11];
  const float* emb_w  = (const float*)d_in[12];
  const float* conv_kw= (const float*)d_in[13];
  const float* fib_kw = (const float*)d_in[14];
  const float* conv_b = (const float*)d_in[15];
  const float* ln_s   = (const float*)d_in[16];
  const float* ln_b   = (const float*)d_in[17];
  const float* l1_w   = (const float*)d_in[18];
  const float* l1_b   = (const float*)d_in[19];
  const float* l2_w   = (const float*)d_in[20];
  const float* l2_b   = (const float*)d_in[21];
  const float* ro_w   = (const float*)d_in[22];
  const float* ro_b   = (const float*)d_in[23];

  float* ws_f   = (float*)d_ws;
  float* g_ori  = ws_f + OFF_ORI;
  float* g_fk   = ws_f + OFF_FK;
  unsigned short* g_fkh = (unsigned short*)(ws_f + OFF_FKH);
  float* g_h    = ws_f + OFF_H;
  unsigned short* g_xnb = (unsigned short*)(ws_f + OFF_XNB);
  float* g_racc = ws_f + OFF_RACC;
  int*   row_ptr= (int*)(ws_f + OFF_RP);
  int*   cursor = (int*)(ws_f + OFF_CUR);
  int*   e0s    = (int*)(ws_f + OFF_E0S);
  float4* rel4  = (float4*)(ws_f + OFF_REL);
  unsigned short* g_wp  = (unsigned short*)(ws_f + OFF_WP);
  unsigned*       g_ckp = (unsigned*)(ws_f + OFF_CKP);
  unsigned short* g_w2f = (unsigned short*)(ws_f + OFF_W2F);
  unsigned*       kb_u  = (unsigned*)(ws_f + OFF_KB);
  float* out_f  = (float*)d_out;

  (void)hipMemsetAsync(g_racc, 0, 240000*sizeof(float), stream);
  k_setup<<<3, 256, 0, stream>>>(fb_w1, fb_b1, fb_w2, fb_b2, fib_kw, g_ori, g_fk, g_fkh);
  k_embed<<<512, 256, 0, stream>>>(x, emb_w, g_h);

  (void)hipMemsetAsync(cursor, 0, (N_+1)*sizeof(int), stream);
  k_count<<<(E_+255)/256, 256, 0, stream>>>(ei, cursor);
  k_scan<<<1, 256, 0, stream>>>(cursor, row_ptr);
  k_scatter<<<(E_+255)/256, 256, 0, stream>>>(pos, ei, cursor, e0s, rel4);
  k_sortbins<<<(N_+255)/256, 256, 0, stream>>>(row_ptr, e0s, rel4);
  k_pack<<<3, 256, 0, stream>>>(l1_w, l2_w, conv_kw, sb_w2, g_wp, g_ckp, g_w2f);
  k_basis_v2<<<3750, 256, 0, stream>>>(rel4, sb_w1, sb_b1, g_w2f, sb_b2, g_ori, kb_u);
  for (int i = 0; i < 3; ++i) {
    k_aggr_f16<<<N_/NPB_, 256, 0, stream>>>(kb_u, row_ptr, e0s, g_ckp + (size_t)i*2048,
                                            g_fkh + (size_t)i*9216, conv_b + i*64,
                                            ln_s + i*64, ln_b + i*64, g_h, g_xnb);
    k_mlp_mfma<<<256, 512, 0, stream>>>(g_xnb, g_h,
                                        g_wp + (size_t)i*32768, g_wp + (size_t)i*32768 + 16384,
                                        l1_b + i*256, l2_b + i*64,
                                        ro_w + i*128, ro_b + i*2, g_racc);
  }
  (void)hipMemsetAsync(out_f, 0, 32*sizeof(float), stream);
  k_final<<<128, 256, 0, stream>>>(g_racc, batch, g_ori, out_f);
}